// Round 8
// baseline (799.464 us; speedup 1.0000x reference)
//
#include <hip/hip_runtime.h>
#include <math.h>

typedef _Float16 f16;
typedef _Float16 f16x8 __attribute__((ext_vector_type(8)));
typedef float f32x4 __attribute__((ext_vector_type(4)));

// ---------------------------------------------------------------------------
// expand_sum_a: x[b,i] = sum_{s<Sin} src[s*plane + b*KIN + i]  (Sin=1: raw input)
// -> Aexp (rows x KIN*19 fp16)
// planes per row: [0,8K): basis-hi | [8K,16K): basis-lo | xh | xh | xl
// ---------------------------------------------------------------------------
__global__ __launch_bounds__(256) void expand_sum_a(
    const float* __restrict__ src, size_t plane, int Sin,
    f16* __restrict__ Aexp, int KIN, int shift)
{
    int idx = blockIdx.x * 256 + threadIdx.x;
    int i = idx & (KIN - 1);
    int b = idx >> shift;
    float x = 0.0f;
    for (int s = 0; s < Sin; ++s) x += src[(size_t)s * plane + idx];

    float xs = (x + 2.2f) * 2.5f;
    float fj = floorf(xs);
    int jj = (int)fj;
    float t = xs - fj;
    float t2 = t * t, t3 = t2 * t;
    float omt = 1.0f - t;
    float p0 = omt * omt * omt * (1.0f / 6.0f);
    float p1 = (3.0f * t3 - 6.0f * t2 + 4.0f) * (1.0f / 6.0f);
    float p2 = (-3.0f * t3 + 3.0f * t2 + 3.0f * t + 1.0f) * (1.0f / 6.0f);
    float p3 = t3 * (1.0f / 6.0f);

    union { f16 h[8]; uint4 v; } hi, lo;
    bool inr = (jj >= 0 && jj <= 10);
    #pragma unroll
    for (int cc = 0; cc < 8; ++cc) {
        int d = cc - (jj - 3);
        float v = 0.0f;
        if (inr) {
            if (d == 0) v = p0; else if (d == 1) v = p1;
            else if (d == 2) v = p2; else if (d == 3) v = p3;
        }
        f16 h = (f16)v;
        hi.h[cc] = h;
        lo.h[cc] = (f16)(v - (float)h);
    }
    size_t KEXP = (size_t)KIN * 19;
    f16* row = Aexp + (size_t)b * KEXP;
    *(uint4*)(row + (size_t)i * 8) = hi.v;
    *(uint4*)(row + (size_t)KIN * 8 + (size_t)i * 8) = lo.v;
    f16 xh = (f16)x;
    f16 xl = (f16)(x - (float)xh);
    int K16 = KIN * 16;
    row[K16 + i] = xh;
    row[K16 + KIN + i] = xh;
    row[K16 + 2 * KIN + i] = xl;
}

// ---------------------------------------------------------------------------
// prep_b (round-3 verified): planes [qw x8][qw x8][wh][wl][wh]
// pairing with A: (bh+bl)*qw + xh*wh + xh*wl + xl*wh
// ---------------------------------------------------------------------------
__global__ __launch_bounds__(256) void prep_b(
    const float* __restrict__ BW, const float* __restrict__ SW,
    f16* __restrict__ Bexp, int KIN, int shift)
{
    int idx = blockIdx.x * 256 + threadIdx.x;
    int i = idx & (KIN - 1);
    int o = idx >> shift;
    const float* sp = SW + ((size_t)o * KIN + i) * 8;
    union { f16 h[8]; uint4 v; } pk;
    #pragma unroll
    for (int cc = 0; cc < 8; ++cc)
        pk.h[cc] = (f16)(rintf(sp[cc] * 32.0f) * 0.03125f);  // n/32, exact in fp16
    size_t KEXP = (size_t)KIN * 19;
    f16* row = Bexp + (size_t)o * KEXP;
    *(uint4*)(row + (size_t)i * 8) = pk.v;
    *(uint4*)(row + (size_t)KIN * 8 + (size_t)i * 8) = pk.v;
    float w = BW[(size_t)o * KIN + i];
    f16 wh = (f16)w;
    f16 wl = (f16)(w - (float)wh);
    int K16 = KIN * 16;
    row[K16 + i] = wh;
    row[K16 + KIN + i] = wl;
    row[K16 + 2 * KIN + i] = wh;
}

// ---------------------------------------------------------------------------
// gemm_mfma R15: 128x128 block tile, 256 threads / 4 waves (2M x 2N), wave
// tile 64x64 (4x4 of 16x16x32 f16, acc = 64 AGPR). BK=32 ring-2 -> 32KB LDS.
// Grid (N/128)*(CH/128)*S = 1024 @ {4096,4} -> 4 blocks/CU (reg cap 128 via
// __launch_bounds__(256,4): acc 64 AGPR + ~60 VGPR fits; degrades to 3/CU
// if slightly over). R7 insight: old kernel was register-limited (100 VGPR
// + 128 AGPR = 228 unified -> 2 waves/SIMD -> 1 block/CU); co-resident
// independent blocks hide the per-tile drain+barrier that capped MfmaUtil
// at 47% for all intra-block schedules (R2-R5).
// Schedule/tile (R3 shape): [8 ds_read (af0,af1,bf0-3 | af2,af3)]
//   [4 gload_lds(t+1)] lgkm(2) 8 MFMA | lgkm(0) 8 MFMA | vmcnt(0) barrier
// Sync ledger (ring-2, prefetch 1, audited):
//   fill: gloads(t) issued during t-1 drained by vmcnt(0) before barrier
//         (end t-1) in every wave -> reads(t) safe.
//   overwrite: gloads(t+1) target slot st^1 (tile t-1); its readers done
//         (own lgkm(0) at t-1) before passing barrier(end t-1); gloads
//         issue after it. NT=1: prologue-only, no loop barrier.
// XOR bank-swizzle (verified invariant: wave row offsets are 16-multiples
// so (row>>1)&3 == (lr>>1)&3): LDS slot (row,kc) holds global kc^((row>>1)&3);
// staging linear-dest, per-lane global kc_src=(lane&3)^((lane>>3)&3);
// read ko=((lane>>4)^((lr>>1)&3))*8. XCD-bijective block swizzle (nwg%8==0).
// ---------------------------------------------------------------------------
__global__ __launch_bounds__(256, 4) void gemm_mfma(
    const f16* __restrict__ A, const f16* __restrict__ Bm,
    float* __restrict__ C, int Kfull, int Kc, size_t plane, int N)
{
    __shared__ __align__(16) f16 As[2][4096];   // [slot][128 rows x 32 k]
    __shared__ __align__(16) f16 Bs[2][4096];

    const int tid = threadIdx.x;
    const int wave = tid >> 6, lane = tid & 63;

    const int nwg = gridDim.x * gridDim.y * gridDim.z;
    const int b = blockIdx.x + gridDim.x * (blockIdx.y + gridDim.y * blockIdx.z);
    const int q = nwg >> 3;
    const int L = (b & 7) * q + (b >> 3);
    const int lx = L % gridDim.x;
    const int rest = L / gridDim.x;
    const int ly = rest % gridDim.y;
    const int lz = rest / gridDim.y;

    const int m0 = ly * 128, n0 = lx * 128;
    const int kb = lz * Kc;
    int kcl = Kfull - kb; if (kcl > Kc) kcl = Kc;
    const int NT = kcl >> 5;

    // staging: 16 chunks of 1KB per tile (A:0..7, B:8..15); wave owns 4.
    const int kc_src = (lane & 3) ^ ((lane >> 3) & 3);
    const f16* gb[4];
    int isA_[4], coff[4];
    #pragma unroll
    for (int j = 0; j < 4; ++j) {
        int cch = wave * 4 + j;          // wave-uniform -> SGPR-friendly
        int a = (cch < 8);
        int c8 = a ? cch : (cch - 8);
        int row0 = (a ? m0 : n0) + c8 * 16 + (lane >> 2);
        gb[j] = (a ? A : Bm) + (size_t)row0 * Kfull + kb + kc_src * 8;
        isA_[j] = a;
        coff[j] = c8 * 512;
    }

    f32x4 acc[4][4];
    #pragma unroll
    for (int i = 0; i < 4; ++i)
        #pragma unroll
        for (int j = 0; j < 4; ++j)
            acc[i][j] = (f32x4){0.f, 0.f, 0.f, 0.f};

    // prologue: tile 0 -> slot 0
    #pragma unroll
    for (int j = 0; j < 4; ++j) {
        f16* dp = isA_[j] ? &As[0][coff[j]] : &Bs[0][coff[j]];
        __builtin_amdgcn_global_load_lds(
            (const __attribute__((address_space(1))) unsigned int*)(gb[j]),
            (__attribute__((address_space(3))) unsigned int*)dp, 16, 0, 0);
    }
    asm volatile("s_waitcnt vmcnt(0)" ::: "memory");
    __builtin_amdgcn_s_barrier();
    asm volatile("" ::: "memory");

    const int lr = lane & 15;
    const int ko = (((lane >> 4) ^ ((lr >> 1) & 3)) & 3) * 8;
    const int wm = (wave >> 1) * 64, wn = (wave & 1) * 64;

    for (int t = 0; t < NT; ++t) {
        const int st = t & 1;
        const int ns = st ^ 1;
        const bool pf = (t + 1 < NT);
        const int kn = (t + 1) << 5;

        f16x8 af[4], bf[4];
        // first 6 reads: af0, af1, bf0..3
        #pragma unroll
        for (int i = 0; i < 2; ++i)
            af[i] = *(const f16x8*)&As[st][(wm + i * 16 + lr) * 32 + ko];
        #pragma unroll
        for (int j = 0; j < 4; ++j)
            bf[j] = *(const f16x8*)&Bs[st][(wn + j * 16 + lr) * 32 + ko];
        __builtin_amdgcn_sched_barrier(0);
        // last 2 reads: af2, af3
        #pragma unroll
        for (int i = 2; i < 4; ++i)
            af[i] = *(const f16x8*)&As[st][(wm + i * 16 + lr) * 32 + ko];
        __builtin_amdgcn_sched_barrier(0);
        // prefetch tile t+1 into the other slot
        if (pf) {
            #pragma unroll
            for (int j = 0; j < 4; ++j) {
                f16* dp = isA_[j] ? &As[ns][coff[j]] : &Bs[ns][coff[j]];
                __builtin_amdgcn_global_load_lds(
                    (const __attribute__((address_space(1))) unsigned int*)(gb[j] + kn),
                    (__attribute__((address_space(3))) unsigned int*)dp, 16, 0, 0);
            }
        }

        // chunk0: af0,af1 x bf (af2,af3 drain underneath)
        asm volatile("s_waitcnt lgkmcnt(2)" ::: "memory");
        __builtin_amdgcn_sched_barrier(0);
        __builtin_amdgcn_s_setprio(1);
        #pragma unroll
        for (int i = 0; i < 2; ++i)
            #pragma unroll
            for (int j = 0; j < 4; ++j)
                acc[i][j] = __builtin_amdgcn_mfma_f32_16x16x32_f16(af[i], bf[j], acc[i][j], 0, 0, 0);
        __builtin_amdgcn_s_setprio(0);

        // chunk1: af2,af3 x bf
        asm volatile("s_waitcnt lgkmcnt(0)" ::: "memory");
        __builtin_amdgcn_sched_barrier(0);
        __builtin_amdgcn_s_setprio(1);
        #pragma unroll
        for (int i = 2; i < 4; ++i)
            #pragma unroll
            for (int j = 0; j < 4; ++j)
                acc[i][j] = __builtin_amdgcn_mfma_f32_16x16x32_f16(af[i], bf[j], acc[i][j], 0, 0, 0);
        __builtin_amdgcn_s_setprio(0);

        if (pf) {
            asm volatile("s_waitcnt vmcnt(0)" ::: "memory");
            __builtin_amdgcn_sched_barrier(0);
            __builtin_amdgcn_s_barrier();
            asm volatile("" ::: "memory");
        }
    }

    // C/D layout: col=lane&15, row=(lane>>4)*4+reg  [m89-verified]
    float* Cp = C + (size_t)lz * plane;
    #pragma unroll
    for (int i = 0; i < 4; ++i) {
        int row = m0 + wm + i * 16 + (lane >> 4) * 4;
        #pragma unroll
        for (int j = 0; j < 4; ++j) {
            int col = n0 + wn + j * 16 + lr;
            #pragma unroll
            for (int rr = 0; rr < 4; ++rr)
                Cp[(size_t)(row + rr) * N + col] = acc[i][j][rr];
        }
    }
}

// ---------------------------------------------------------------------------
// Fallback fp32 GEMM (round-1 verified, used only if ws_size tiny)
// ---------------------------------------------------------------------------
__global__ __launch_bounds__(256) void kan_gemm(
    const float* __restrict__ X, const float* __restrict__ BW,
    const float* __restrict__ SW, float* __restrict__ Y, int KIN, int OUT)
{
    __shared__ __align__(16) float Asf[72][68];
    __shared__ __align__(16) float Bsf[72][68];
    const int tid = threadIdx.x;
    const int n0 = blockIdx.x * 64;
    const int m0 = blockIdx.y * 64;
    const int tx = tid & 15;
    const int ty = tid >> 4;
    float acc[4][4] = {};
    for (int k0 = 0; k0 < KIN; k0 += 8) {
        #pragma unroll
        for (int rep = 0; rep < 2; ++rep) {
            int idx = rep * 256 + tid;
            int r = idx >> 3, c = idx & 7;
            float x = X[(size_t)(m0 + r) * KIN + k0 + c];
            int bk = c * 9;
            Asf[bk][r] = x;
            #pragma unroll
            for (int z = 0; z < 8; ++z) Asf[bk + 1 + z][r] = 0.0f;
            float xs = (x + 2.2f) * 2.5f;
            float fj = floorf(xs);
            int j = (int)fj;
            if (j >= 0 && j <= 10) {
                float t = xs - fj;
                float t2 = t * t, t3 = t2 * t;
                float omt = 1.0f - t;
                float p0 = omt * omt * omt * (1.0f / 6.0f);
                float p1 = (3.0f * t3 - 6.0f * t2 + 4.0f) * (1.0f / 6.0f);
                float p2 = (-3.0f * t3 + 3.0f * t2 + 3.0f * t + 1.0f) * (1.0f / 6.0f);
                float p3 = t3 * (1.0f / 6.0f);
                if (j >= 3) Asf[bk + 1 + j - 3][r] = p0;
                if (j >= 2 && j <= 9) Asf[bk + 1 + j - 2][r] = p1;
                if (j >= 1 && j <= 8) Asf[bk + 1 + j - 1][r] = p2;
                if (j <= 7) Asf[bk + 1 + j][r] = p3;
            }
        }
        #pragma unroll
        for (int rep = 0; rep < 16; ++rep) {
            int idx = rep * 256 + tid;
            int ol = idx >> 6;
            int l = idx & 63;
            int i = l >> 3, cc = l & 7;
            float v = SW[((size_t)(n0 + ol) * KIN + k0 + i) * 8 + cc];
            Bsf[i * 9 + 1 + cc][ol] = rintf(v * 32.0f) * 0.03125f;
        }
        #pragma unroll
        for (int rep = 0; rep < 2; ++rep) {
            int idx = rep * 256 + tid;
            int ol = idx >> 3, cc = idx & 7;
            Bsf[cc * 9][ol] = BW[(size_t)(n0 + ol) * KIN + k0 + cc];
        }
        __syncthreads();
        #pragma unroll 8
        for (int kk = 0; kk < 72; ++kk) {
            float4 av = *(const float4*)&Asf[kk][ty * 4];
            float4 bv = *(const float4*)&Bsf[kk][tx * 4];
            acc[0][0] += av.x * bv.x; acc[0][1] += av.x * bv.y; acc[0][2] += av.x * bv.z; acc[0][3] += av.x * bv.w;
            acc[1][0] += av.y * bv.x; acc[1][1] += av.y * bv.y; acc[1][2] += av.y * bv.z; acc[1][3] += av.y * bv.w;
            acc[2][0] += av.z * bv.x; acc[2][1] += av.z * bv.y; acc[2][2] += av.z * bv.z; acc[2][3] += av.z * bv.w;
            acc[3][0] += av.w * bv.x; acc[3][1] += av.w * bv.y; acc[3][2] += av.w * bv.z; acc[3][3] += av.w * bv.w;
        }
        __syncthreads();
    }
    #pragma unroll
    for (int i = 0; i < 4; ++i) {
        float4 o = make_float4(acc[i][0], acc[i][1], acc[i][2], acc[i][3]);
        *(float4*)&Y[(size_t)(m0 + ty * 4 + i) * OUT + n0 + tx * 4] = o;
    }
}

// ---------------------------------------------------------------------------
// huxley_rd R13 (R6-verified): PAIRED rows, z = u1 + i*u2; 3 complex FFTs
// per TWO rows. See R6 ledger for exact-split derivation (gate real-even,
// phase conj-symmetric, bin-512 cos-only, sAbs via F1/F2 separation).
// ---------------------------------------------------------------------------
__device__ __forceinline__ float2 block_reduce_sum2(float2 v, float2* red, int tid) {
    red[tid] = v; __syncthreads();
    #pragma unroll
    for (int s = 128; s > 0; s >>= 1) {
        if (tid < s) {
            red[tid].x += red[tid + s].x;
            red[tid].y += red[tid + s].y;
        }
        __syncthreads();
    }
    float2 r = red[0]; __syncthreads();
    return r;
}
__device__ __forceinline__ float2 block_reduce_min2(float2 v, float2* red, int tid) {
    red[tid] = v; __syncthreads();
    #pragma unroll
    for (int s = 128; s > 0; s >>= 1) {
        if (tid < s) {
            red[tid].x = fminf(red[tid].x, red[tid + s].x);
            red[tid].y = fminf(red[tid].y, red[tid + s].y);
        }
        __syncthreads();
    }
    float2 r = red[0]; __syncthreads();
    return r;
}

__device__ void fft1024(float2* X, const float2* tw, int tid, bool inverse) {
    if (!inverse) {
        for (int sh = 9; sh >= 0; --sh) {
            int h = 1 << sh;
            #pragma unroll
            for (int q = 0; q < 2; ++q) {
                int b = tid + q * 256;
                int g = b >> sh, j = b & (h - 1);
                int i0 = (g << (sh + 1)) + j, i1 = i0 + h;
                float2 u = X[i0], v = X[i1];
                float dx = u.x - v.x, dy = u.y - v.y;
                X[i0] = make_float2(u.x + v.x, u.y + v.y);
                float2 w = tw[j << (9 - sh)];
                X[i1] = make_float2(dx * w.x + dy * w.y, dy * w.x - dx * w.y);
            }
            __syncthreads();
        }
    } else {
        for (int sh = 0; sh <= 9; ++sh) {
            int h = 1 << sh;
            #pragma unroll
            for (int q = 0; q < 2; ++q) {
                int b = tid + q * 256;
                int g = b >> sh, j = b & (h - 1);
                int i0 = (g << (sh + 1)) + j, i1 = i0 + h;
                float2 u = X[i0], v = X[i1];
                float2 w = tw[j << (9 - sh)];
                float tx2 = v.x * w.x - v.y * w.y;
                float ty2 = v.x * w.y + v.y * w.x;
                X[i0] = make_float2(u.x + tx2, u.y + ty2);
                X[i1] = make_float2(u.x - tx2, u.y - ty2);
            }
            __syncthreads();
        }
    }
}

__global__ __launch_bounds__(256) void huxley_kernel(
    const float* __restrict__ Pin, size_t plane, int S,
    float* __restrict__ dst,
    const float* __restrict__ sg, const float* __restrict__ dk,
    const float* __restrict__ pa, const float* __restrict__ pgam,
    const float* __restrict__ ptau, const float* __restrict__ pvel,
    const float* __restrict__ gp, const float* __restrict__ chi)
{
    __shared__ float2 A[1024];
    __shared__ float2 Bb[1024];
    __shared__ float2 sErg[1024];
    __shared__ float sAbs1[516];
    __shared__ float sAbs2[516];
    __shared__ float2 tw[512];
    __shared__ float2 red2[256];
    __shared__ float sG[516];

    const int tid = threadIdx.x;
    const int r0 = blockIdx.x * 2;
    const float* pin0 = Pin + (size_t)r0 * 1024;
    const float* pin1 = Pin + (size_t)(r0 + 1) * 1024;
    float* uo0 = dst + (size_t)r0 * 1024;
    float* uo1 = dst + (size_t)(r0 + 1) * 1024;

    for (int m = tid; m < 512; m += 256) {
        float s, c;
        sincosf(6.283185307179586f * (float)m * (1.0f / 1024.0f), &s, &c);
        tw[m] = make_float2(c, s);
    }
    for (int k = tid; k < 513; k += 256)
        sG[k] = 1.0f / (1.0f + expf(-sg[k]));
    for (int i = tid; i < 1024; i += 256) {
        float s0 = 0.0f, s1 = 0.0f;
        for (int ss = 0; ss < S; ++ss) {
            s0 += pin0[(size_t)ss * plane + i];
            s1 += pin1[(size_t)ss * plane + i];
        }
        A[i] = make_float2(s0, s1);   // packed: row1 + i*row2
    }
    __syncthreads();

    fft1024(A, tw, tid, false);       // A = Z (bit-reversed order)

    for (int p = tid; p < 1024; p += 256) {
        int k = (int)(__brev((unsigned)p) >> 22);
        int m = (k <= 512) ? k : 1024 - k;
        float g = sG[m] * (1.0f / 1024.0f);
        Bb[p] = make_float2(A[p].x * g, A[p].y * g);
    }
    __syncthreads();
    fft1024(Bb, tw, tid, true);
    for (int i = tid; i < 1024; i += 256) sErg[i] = Bb[i];
    __syncthreads();

    const float vv = pvel[0];
    for (int p = tid; p < 1024; p += 256) {
        int k = (int)(__brev((unsigned)p) >> 22);
        int m = (k <= 512) ? k : 1024 - k;
        float omg = 1.0f - sG[m];
        float2 z = A[p];
        float nx = z.x * omg, ny = z.y * omg;
        float ang = (k <= 512)
            ? (-6.283185307179586f * vv * (float)k * (1.0f / 1024.0f))
            : (6.283185307179586f * vv * (float)(1024 - k) * (1.0f / 1024.0f));
        float sn, cs;
        sincosf(ang, &sn, &cs);
        float yx, yy;
        if (k == 512) {
            yx = nx * cs;
            yy = ny * cs;
            sAbs1[512] = fabsf(nx * cs);
            sAbs2[512] = fabsf(ny * cs);
        } else {
            yx = nx * cs - ny * sn;
            yy = nx * sn + ny * cs;
            if (k < 512) {
                int p2 = (int)(__brev((unsigned)((1024 - k) & 1023)) >> 22);
                float2 z2 = A[p2];
                float f1x = 0.5f * (z.x + z2.x), f1y = 0.5f * (z.y - z2.y);
                float f2x = 0.5f * (z.y + z2.y), f2y = 0.5f * (z2.x - z.x);
                sAbs1[k] = omg * sqrtf(f1x * f1x + f1y * f1y);
                sAbs2[k] = omg * sqrtf(f2x * f2x + f2y * f2y);
            }
        }
        Bb[p] = make_float2(yx * (1.0f / 1024.0f), yy * (1.0f / 1024.0f));
    }
    __syncthreads();
    fft1024(Bb, tw, tid, true);

    float2 loc = make_float2(0.0f, 0.0f);
    for (int i = tid; i < 1024; i += 256) {
        loc.x += Bb[i].x * Bb[i].x;
        loc.y += Bb[i].y * Bb[i].y;
    }
    float2 trc = block_reduce_sum2(loc, red2, tid);

    loc = make_float2(0.0f, 0.0f);
    for (int k = tid; k < 513; k += 256) { loc.x += sAbs1[k]; loc.y += sAbs2[k]; }
    float2 msum = block_reduce_sum2(loc, red2, tid);
    float2 mean = make_float2(msum.x * (1.0f / 513.0f), msum.y * (1.0f / 513.0f));

    loc = make_float2(0.0f, 0.0f);
    for (int k = tid; k < 513; k += 256) {
        float d1 = sAbs1[k] - mean.x;
        float d2 = sAbs2[k] - mean.y;
        loc.x += d1 * d1; loc.y += d2 * d2;
    }
    float2 varsum = block_reduce_sum2(loc, red2, tid);

    loc = make_float2(3.4e38f, 3.4e38f);
    for (int k = tid; k < 513; k += 256) {
        loc.x = fminf(loc.x, sAbs1[k]);
        loc.y = fminf(loc.y, sAbs2[k]);
    }
    float2 lmin = block_reduce_min2(loc, red2, tid);

    const float tauv = ptau[0];
    float trcv[2]  = { trc.x, trc.y };
    float varv[2]  = { varsum.x, varsum.y };
    float lminv[2] = { lmin.x, lmin.y };
    float gpv[2]   = { gp[r0], gp[r0 + 1] };
    float chv[2]   = { chi[r0], chi[r0 + 1] };
    float cb[2];
    #pragma unroll
    for (int rr = 0; rr < 2; ++rr) {
        float det_pas = varv[rr] * (1.0f / 512.0f) + 1e-6f;
        float sd = sqrtf(det_pas);
        float denom = 2.0f * sd * sd * sd + 1e-8f;
        float c3 = (3.0f * gpv[rr] - trcv[rr] / tauv) / denom;
        c3 = fminf(fmaxf(c3, -0.999f), 0.999f);
        float ph = acosf(c3) * (1.0f / 3.0f);
        float amp = 2.0f * sqrtf(lminv[rr] * (1.0f / 3.0f) + 1e-8f);
        float nu = sqrtf(trcv[rr]);
        float achi = fabsf(chv[rr]);
        float cbest = 0.0f, ebest = -1.0f;
        #pragma unroll
        for (int kb = 0; kb < 3; ++kb) {
            float ck = amp * cosf(ph + 2.0943951023931953f * (float)kb) * expf(-achi * (float)kb);
            float ek = fabsf(ck) * nu;
            if (ek > ebest) { ebest = ek; cbest = ck; }
        }
        cb[rr] = cbest;
    }

    const float a = pa[0], gm = pgam[0];
    const float k0 = dk[0], k1 = dk[1], k2 = dk[2];
    for (int i = tid; i < 1024; i += 256) {
        float2 e = sErg[i];
        float2 l = (i > 0) ? sErg[i - 1] : make_float2(0.0f, 0.0f);
        float2 r = (i < 1023) ? sErg[i + 1] : make_float2(0.0f, 0.0f);
        float reac1 = e.x * (e.x - a) * (1.0f - e.x);
        float diff1 = k0 * l.x + k1 * e.x + k2 * r.x;
        float un1 = e.x + 0.1f * (reac1 + gm * diff1);
        float s1 = un1 + cb[0] * Bb[i].x;
        uo0[i] = s1 / (1.0f + expf(-s1));
        float reac2 = e.y * (e.y - a) * (1.0f - e.y);
        float diff2 = k0 * l.y + k1 * e.y + k2 * r.y;
        float un2 = e.y + 0.1f * (reac2 + gm * diff2);
        float s2 = un2 + cb[1] * Bb[i].y;
        uo1[i] = s2 / (1.0f + expf(-s2));
    }
}

// ---------------------------------------------------------------------------

extern "C" void kernel_launch(void* const* d_in, const int* in_sizes, int n_in,
                              void* d_out, int out_size, void* d_ws, size_t ws_size,
                              hipStream_t stream) {
    const float* c    = (const float*)d_in[0];
    const float* bw0  = (const float*)d_in[1];
    const float* sw0  = (const float*)d_in[2];
    const float* bw1  = (const float*)d_in[3];
    const float* sw1  = (const float*)d_in[4];
    const float* bw2  = (const float*)d_in[5];
    const float* sw2  = (const float*)d_in[6];
    const float* sg   = (const float*)d_in[7];
    const float* dk   = (const float*)d_in[8];
    const float* pa   = (const float*)d_in[9];
    const float* pgam = (const float*)d_in[10];
    const float* ptau = (const float*)d_in[11];
    const float* pvel = (const float*)d_in[12];
    const float* gp   = (const float*)d_in[13];
    const float* chi  = (const float*)d_in[14];

    const int B = 4096, NIN = 512, W = 1024, NOUT = 1024;
    const int KE0 = 19 * NIN, KE1 = 19 * W;
    const size_t MN = (size_t)B * W;
    const size_t BE = (size_t)W * KE1 * 2;      // Bexp bytes (39.85 MB)
    dim3 blk(256);

    // ---- pick (CH, S): {4096,4} -> gemm grid 8x32x4 = 1024 = 4 blocks/CU ----
    struct Cand { int CH, S; };
    const Cand cands[] = {
        {4096, 4}, {4096, 3}, {2048, 4}, {2048, 3}, {1024, 4},
        {512, 4}, {256, 4}
    };
    int CH = 0, S = 1;
    for (const auto& cd : cands) {
        size_t need = BE + (size_t)cd.CH * KE1 * 2 + (size_t)cd.S * MN * 4;
        if (need <= ws_size) { CH = cd.CH; S = cd.S; break; }
    }

    if (CH > 0) {
        f16* Bexp = (f16*)d_ws;
        float* P  = (float*)((char*)d_ws + BE);                // S planes of M x N fp32
        f16* Aexp = (f16*)((char*)d_ws + BE + (size_t)S * MN * 4);

        // ceil-split Kc (multiple of 32); kernel clamps last split
        const int Kc0 = ((KE0 / 32 + S - 1) / S) * 32;
        const int Kc1 = ((KE1 / 32 + S - 1) / S) * 32;

        // ---- layer 0: KIN=512 ----
        prep_b<<<(W * NIN) / 256, blk, 0, stream>>>(bw0, sw0, Bexp, NIN, 9);
        for (int r0 = 0; r0 < B; r0 += CH) {
            expand_sum_a<<<(CH * NIN) / 256, blk, 0, stream>>>(
                c + (size_t)r0 * NIN, 0, 1, Aexp, NIN, 9);
            gemm_mfma<<<dim3(W / 128, CH / 128, S), blk, 0, stream>>>(
                Aexp, Bexp, P + (size_t)r0 * W, KE0, Kc0, MN, W);
        }
        // ---- layer 1: KIN=1024 ----
        prep_b<<<(W * W) / 256, blk, 0, stream>>>(bw1, sw1, Bexp, W, 10);
        for (int r0 = 0; r0 < B; r0 += CH) {
            expand_sum_a<<<(CH * W) / 256, blk, 0, stream>>>(
                P + (size_t)r0 * W, MN, S, Aexp, W, 10);
            gemm_mfma<<<dim3(W / 128, CH / 128, S), blk, 0, stream>>>(
                Aexp, Bexp, P + (size_t)r0 * W, KE1, Kc1, MN, W);
        }
        // ---- layer 2 ----
        prep_b<<<(NOUT * W) / 256, blk, 0, stream>>>(bw2, sw2, Bexp, W, 10);
        for (int r0 = 0; r0 < B; r0 += CH) {
            expand_sum_a<<<(CH * W) / 256, blk, 0, stream>>>(
                P + (size_t)r0 * W, MN, S, Aexp, W, 10);
            gemm_mfma<<<dim3(NOUT / 128, CH / 128, S), blk, 0, stream>>>(
                Aexp, Bexp, P + (size_t)r0 * W, KE1, Kc1, MN, NOUT);
        }
        huxley_kernel<<<B / 2, blk, 0, stream>>>(P, MN, S, (float*)d_out,
                                                 sg, dk, pa, pgam, ptau, pvel, gp, chi);
    } else {
        // fallback: round-1 fp32 path (needs only 33.6 MB ws)
        float* fx0 = (float*)d_ws;
        float* fx1 = fx0 + (size_t)B * W;
        dim3 g0(W / 64, B / 64);
        kan_gemm<<<g0, blk, 0, stream>>>(c,   bw0, sw0, fx0, NIN, W);
        kan_gemm<<<g0, blk, 0, stream>>>(fx0, bw1, sw1, fx1, W,   W);
        dim3 g2(NOUT / 64, B / 64);
        kan_gemm<<<g2, blk, 0, stream>>>(fx1, bw2, sw2, (float*)d_out, W, NOUT);
        huxley_kernel<<<B / 2, blk, 0, stream>>>((float*)d_out, 0, 1, (float*)d_out,
                                                 sg, dk, pa, pgam, ptau, pvel, gp, chi);
    }
}

// Round 10
// 681.295 us; speedup vs baseline: 1.1734x; 1.1734x over previous
//
#include <hip/hip_runtime.h>
#include <math.h>

typedef _Float16 f16;
typedef _Float16 f16x8 __attribute__((ext_vector_type(8)));
typedef float f32x4 __attribute__((ext_vector_type(4)));

// ---------------------------------------------------------------------------
// expand_sum_a: x[b,i] = sum_{s<Sin} src[s*plane + b*KIN + i]  (Sin=1: raw input)
// -> Aexp (rows x KIN*19 fp16)
// planes per row: [0,8K): basis-hi | [8K,16K): basis-lo | xh | xh | xl
// ---------------------------------------------------------------------------
__global__ __launch_bounds__(256) void expand_sum_a(
    const float* __restrict__ src, size_t plane, int Sin,
    f16* __restrict__ Aexp, int KIN, int shift)
{
    int idx = blockIdx.x * 256 + threadIdx.x;
    int i = idx & (KIN - 1);
    int b = idx >> shift;
    float x = 0.0f;
    for (int s = 0; s < Sin; ++s) x += src[(size_t)s * plane + idx];

    float xs = (x + 2.2f) * 2.5f;
    float fj = floorf(xs);
    int jj = (int)fj;
    float t = xs - fj;
    float t2 = t * t, t3 = t2 * t;
    float omt = 1.0f - t;
    float p0 = omt * omt * omt * (1.0f / 6.0f);
    float p1 = (3.0f * t3 - 6.0f * t2 + 4.0f) * (1.0f / 6.0f);
    float p2 = (-3.0f * t3 + 3.0f * t2 + 3.0f * t + 1.0f) * (1.0f / 6.0f);
    float p3 = t3 * (1.0f / 6.0f);

    union { f16 h[8]; uint4 v; } hi, lo;
    bool inr = (jj >= 0 && jj <= 10);
    #pragma unroll
    for (int cc = 0; cc < 8; ++cc) {
        int d = cc - (jj - 3);
        float v = 0.0f;
        if (inr) {
            if (d == 0) v = p0; else if (d == 1) v = p1;
            else if (d == 2) v = p2; else if (d == 3) v = p3;
        }
        f16 h = (f16)v;
        hi.h[cc] = h;
        lo.h[cc] = (f16)(v - (float)h);
    }
    size_t KEXP = (size_t)KIN * 19;
    f16* row = Aexp + (size_t)b * KEXP;
    *(uint4*)(row + (size_t)i * 8) = hi.v;
    *(uint4*)(row + (size_t)KIN * 8 + (size_t)i * 8) = lo.v;
    f16 xh = (f16)x;
    f16 xl = (f16)(x - (float)xh);
    int K16 = KIN * 16;
    row[K16 + i] = xh;
    row[K16 + KIN + i] = xh;
    row[K16 + 2 * KIN + i] = xl;
}

// ---------------------------------------------------------------------------
// prep_b (round-3 verified): planes [qw x8][qw x8][wh][wl][wh]
// pairing with A: (bh+bl)*qw + xh*wh + xh*wl + xl*wh
// ---------------------------------------------------------------------------
__global__ __launch_bounds__(256) void prep_b(
    const float* __restrict__ BW, const float* __restrict__ SW,
    f16* __restrict__ Bexp, int KIN, int shift)
{
    int idx = blockIdx.x * 256 + threadIdx.x;
    int i = idx & (KIN - 1);
    int o = idx >> shift;
    const float* sp = SW + ((size_t)o * KIN + i) * 8;
    union { f16 h[8]; uint4 v; } pk;
    #pragma unroll
    for (int cc = 0; cc < 8; ++cc)
        pk.h[cc] = (f16)(rintf(sp[cc] * 32.0f) * 0.03125f);  // n/32, exact in fp16
    size_t KEXP = (size_t)KIN * 19;
    f16* row = Bexp + (size_t)o * KEXP;
    *(uint4*)(row + (size_t)i * 8) = pk.v;
    *(uint4*)(row + (size_t)KIN * 8 + (size_t)i * 8) = pk.v;
    float w = BW[(size_t)o * KIN + i];
    f16 wh = (f16)w;
    f16 wl = (f16)(w - (float)wh);
    int K16 = KIN * 16;
    row[K16 + i] = wh;
    row[K16 + KIN + i] = wl;
    row[K16 + 2 * KIN + i] = wh;
}

// ---------------------------------------------------------------------------
// gemm_mfma R16 (resubmit; R9 run died to container infra, no data):
// faithful m201-style quadrant pipeline.
// 256x256 tile, 512 thr / 8 waves (2M x 4N), wave tile 128x64. BK=64,
// 2 bufs x 4 half-tiles (Ah0,Ah1,Bh0,Bh1; 16KB each) = 128KB LDS.
// Half-tiles defined QUADRANT-wise so each phase reads exactly one:
//   A half h = rows with ((r>>6)&1)==h  -> idx(r) = (r&63) + (r>>7)*64
//   B half h = cols with ((c>>5)&1)==h  -> idx(c) = (c&31) + (c>>6)*32
// 4 phases per K-tile; per phase: {ds_reads for this phase's quadrant |
// stage ONE half-tile of tile t+1 | counted vmcnt(4) | barrier | lgkm(0) |
// setprio 16 MFMA}. Quadrant rotation Q00,Q01,Q10,Q11 reuses B-half regs
// across 2 phases; acc-reuse distance 4 phases.
// Stage order per tile: Ah0@ph0, Bh0@ph1, Bh1@ph2, Ah1@ph3.
// Wait ledger (re-audited R9->R10, invariant = 4 outstanding at tile top):
//   ph0 vmcnt(4): retires Bh1(t) [read ph1]   (lag 2 phases ~1100cyc > HBM)
//   ph1 vmcnt(4): retires Ah1(t) [read ph2]
//   ph3 vmcnt(4): retires Ah0,Bh0(t+1) [read t+1.ph0]
//   last tile: ph0 vmcnt(2), ph1 vmcnt(0), no ph3 wait/barrier.
// Barriers: ph0, ph1, ph3 only (ph2's reads are published by ph1's barrier;
// ph3's MFMA is reg-only). Overwrite hazard: any half-slot's last reader
// completed (own lgkm(0)) >=1 barrier before its restage -> safe. All
// barriers block-uniform (pf/NT uniform) -> no divergent-barrier hang.
// Swizzle (R5-verified conflict-free, 128B rows, 8 x 16B slots): phys slot s
// at idx i holds global chunk s ^ (i&7); staging linear LDS dest with
// per-lane global kc_src = (lane&7)^(lane>>3); read phys = (ks*4+g4)^(lr&7).
// XCD-bijective block swizzle (nwg%8==0). C/D layout m89-verified.
// ---------------------------------------------------------------------------
#define GLD16(dst, src) __builtin_amdgcn_global_load_lds( \
    (const __attribute__((address_space(1))) unsigned int*)(src), \
    (__attribute__((address_space(3))) unsigned int*)(dst), 16, 0, 0)

__global__ __launch_bounds__(512, 2) void gemm_mfma(
    const f16* __restrict__ A, const f16* __restrict__ Bm,
    float* __restrict__ C, int Kfull, int Kc, size_t plane, int N)
{
    __shared__ __align__(16) f16 As[4][8192];   // [buf*2+half][128 idx x 64 k]
    __shared__ __align__(16) f16 Bs[4][8192];

    const int tid = threadIdx.x;
    const int wave = tid >> 6, lane = tid & 63;

    // ---- XCD-aware bijective swizzle ----
    const int nwg = gridDim.x * gridDim.y * gridDim.z;
    const int b = blockIdx.x + gridDim.x * (blockIdx.y + gridDim.y * blockIdx.z);
    const int q = nwg >> 3;
    const int L = (b & 7) * q + (b >> 3);
    const int lx = L % gridDim.x;
    const int rest = L / gridDim.x;
    const int ly = rest % gridDim.y;
    const int lz = rest / gridDim.y;

    const int m0 = ly * 256, n0 = lx * 256;
    const int kb = lz * Kc;
    int kcl = Kfull - kb; if (kcl > Kc) kcl = Kc;
    const int NT = kcl >> 6;

    // ---- staging bases: per half-tile a wave issues 2 gloads (g = wave*2+j),
    // each covering idx rows g*8..g*8+7; lane l -> idx g*8+(l>>3), slot l&7.
    const int l3 = lane >> 3;                  // 0..7
    const int kc_src = ((lane & 7) ^ l3);      // swizzled global 16B chunk
    const f16* pA[2][2];                       // [half][j]
    const f16* pB[2][2];
    #pragma unroll
    for (int h = 0; h < 2; ++h) {
        #pragma unroll
        for (int j = 0; j < 2; ++j) {
            int g = wave * 2 + j;
            int rA = g * 8 + l3 + h * 64 + ((g >= 8) ? 64 : 0);
            int cB = (g * 8 & 31) + l3 + (g >> 2) * 64 + h * 32;
            pA[h][j] = A  + (size_t)(m0 + rA) * Kfull + kb + kc_src * 8;
            pB[h][j] = Bm + (size_t)(n0 + cB) * Kfull + kb + kc_src * 8;
        }
    }
    const int dst0 = (wave * 2) * 512 + lane * 8;       // f16 offset in half-slot
    const int dst1 = (wave * 2 + 1) * 512 + lane * 8;

    #define STAGE_A(buf, h, koff) do { \
        GLD16(&As[(buf)*2+(h)][dst0], pA[h][0] + (koff)); \
        GLD16(&As[(buf)*2+(h)][dst1], pA[h][1] + (koff)); } while (0)
    #define STAGE_B(buf, h, koff) do { \
        GLD16(&Bs[(buf)*2+(h)][dst0], pB[h][0] + (koff)); \
        GLD16(&Bs[(buf)*2+(h)][dst1], pB[h][1] + (koff)); } while (0)

    f32x4 acc[8][4];
    #pragma unroll
    for (int i = 0; i < 8; ++i)
        #pragma unroll
        for (int j = 0; j < 4; ++j)
            acc[i][j] = (f32x4){0.f, 0.f, 0.f, 0.f};

    // prologue: tile 0 -> buf 0, steady-state issue order Ah0,Bh0,Bh1,Ah1
    STAGE_A(0, 0, 0);
    STAGE_B(0, 0, 0);
    STAGE_B(0, 1, 0);
    STAGE_A(0, 1, 0);
    asm volatile("s_waitcnt vmcnt(4)" ::: "memory");   // Ah0,Bh0 resident
    __builtin_amdgcn_s_barrier();
    asm volatile("" ::: "memory");

    const int lr = lane & 15;
    const int g4 = lane >> 4;                  // k-chunk group within K=32
    const int swz = lr & 7;
    const int ko0 = ((g4)     ^ swz) * 8;      // ks=0 phys slot -> f16 offset
    const int ko1 = ((4 + g4) ^ swz) * 8;      // ks=1
    const int aid = (wave & 1) * 64;           // A idx base (wave M-half)
    const int bid = (wave >> 1) * 32;          // B idx base (wave N-group)
    const int wm = (wave & 1) * 128, wn = (wave >> 1) * 64;

    f16x8 afr[4][2], bfr[2][2][2];             // afr[mf][ks]; bfr[p][nf][ks]

    for (int t = 0; t < NT; ++t) {
        const int rb = t & 1, wb = rb ^ 1;
        const bool pf = (t + 1 < NT);
        const int kt = (t + 1) << 6;

        // ================= ph0: Q(0,0) =================
        #pragma unroll
        for (int mf = 0; mf < 4; ++mf) {
            afr[mf][0] = *(const f16x8*)&As[rb * 2 + 0][(aid + mf * 16 + lr) * 64 + ko0];
            afr[mf][1] = *(const f16x8*)&As[rb * 2 + 0][(aid + mf * 16 + lr) * 64 + ko1];
        }
        #pragma unroll
        for (int nf = 0; nf < 2; ++nf) {
            bfr[0][nf][0] = *(const f16x8*)&Bs[rb * 2 + 0][(bid + nf * 16 + lr) * 64 + ko0];
            bfr[0][nf][1] = *(const f16x8*)&Bs[rb * 2 + 0][(bid + nf * 16 + lr) * 64 + ko1];
        }
        __builtin_amdgcn_sched_barrier(0);
        if (pf) STAGE_A(wb, 0, kt);
        if (pf) asm volatile("s_waitcnt vmcnt(4)" ::: "memory");
        else    asm volatile("s_waitcnt vmcnt(2)" ::: "memory");
        __builtin_amdgcn_sched_barrier(0);
        __builtin_amdgcn_s_barrier();
        asm volatile("s_waitcnt lgkmcnt(0)" ::: "memory");
        __builtin_amdgcn_sched_barrier(0);
        __builtin_amdgcn_s_setprio(1);
        #pragma unroll
        for (int mf = 0; mf < 4; ++mf)
            #pragma unroll
            for (int nf = 0; nf < 2; ++nf) {
                acc[mf][nf] = __builtin_amdgcn_mfma_f32_16x16x32_f16(afr[mf][0], bfr[0][nf][0], acc[mf][nf], 0, 0, 0);
                acc[mf][nf] = __builtin_amdgcn_mfma_f32_16x16x32_f16(afr[mf][1], bfr[0][nf][1], acc[mf][nf], 0, 0, 0);
            }
        __builtin_amdgcn_s_setprio(0);

        // ================= ph1: Q(0,1) =================
        #pragma unroll
        for (int nf = 0; nf < 2; ++nf) {
            bfr[1][nf][0] = *(const f16x8*)&Bs[rb * 2 + 1][(bid + nf * 16 + lr) * 64 + ko0];
            bfr[1][nf][1] = *(const f16x8*)&Bs[rb * 2 + 1][(bid + nf * 16 + lr) * 64 + ko1];
        }
        __builtin_amdgcn_sched_barrier(0);
        if (pf) STAGE_B(wb, 0, kt);
        if (pf) asm volatile("s_waitcnt vmcnt(4)" ::: "memory");
        else    asm volatile("s_waitcnt vmcnt(0)" ::: "memory");
        __builtin_amdgcn_sched_barrier(0);
        __builtin_amdgcn_s_barrier();
        asm volatile("s_waitcnt lgkmcnt(0)" ::: "memory");
        __builtin_amdgcn_sched_barrier(0);
        __builtin_amdgcn_s_setprio(1);
        #pragma unroll
        for (int mf = 0; mf < 4; ++mf)
            #pragma unroll
            for (int nf = 0; nf < 2; ++nf) {
                acc[mf][2 + nf] = __builtin_amdgcn_mfma_f32_16x16x32_f16(afr[mf][0], bfr[1][nf][0], acc[mf][2 + nf], 0, 0, 0);
                acc[mf][2 + nf] = __builtin_amdgcn_mfma_f32_16x16x32_f16(afr[mf][1], bfr[1][nf][1], acc[mf][2 + nf], 0, 0, 0);
            }
        __builtin_amdgcn_s_setprio(0);

        // ================= ph2: Q(1,0) (no barrier: reads published @ph1) ==
        #pragma unroll
        for (int mf = 0; mf < 4; ++mf) {
            afr[mf][0] = *(const f16x8*)&As[rb * 2 + 1][(aid + mf * 16 + lr) * 64 + ko0];
            afr[mf][1] = *(const f16x8*)&As[rb * 2 + 1][(aid + mf * 16 + lr) * 64 + ko1];
        }
        __builtin_amdgcn_sched_barrier(0);
        if (pf) STAGE_B(wb, 1, kt);
        asm volatile("s_waitcnt lgkmcnt(0)" ::: "memory");
        __builtin_amdgcn_sched_barrier(0);
        __builtin_amdgcn_s_setprio(1);
        #pragma unroll
        for (int mf = 0; mf < 4; ++mf)
            #pragma unroll
            for (int nf = 0; nf < 2; ++nf) {
                acc[4 + mf][nf] = __builtin_amdgcn_mfma_f32_16x16x32_f16(afr[mf][0], bfr[0][nf][0], acc[4 + mf][nf], 0, 0, 0);
                acc[4 + mf][nf] = __builtin_amdgcn_mfma_f32_16x16x32_f16(afr[mf][1], bfr[0][nf][1], acc[4 + mf][nf], 0, 0, 0);
            }
        __builtin_amdgcn_s_setprio(0);

        // ================= ph3: Q(1,1) (reg-only MFMA first) ===============
        __builtin_amdgcn_s_setprio(1);
        #pragma unroll
        for (int mf = 0; mf < 4; ++mf)
            #pragma unroll
            for (int nf = 0; nf < 2; ++nf) {
                acc[4 + mf][2 + nf] = __builtin_amdgcn_mfma_f32_16x16x32_f16(afr[mf][0], bfr[1][nf][0], acc[4 + mf][2 + nf], 0, 0, 0);
                acc[4 + mf][2 + nf] = __builtin_amdgcn_mfma_f32_16x16x32_f16(afr[mf][1], bfr[1][nf][1], acc[4 + mf][2 + nf], 0, 0, 0);
            }
        __builtin_amdgcn_s_setprio(0);
        if (pf) {
            STAGE_A(wb, 1, kt);
            asm volatile("s_waitcnt vmcnt(4)" ::: "memory");  // Ah0,Bh0(t+1) resident
            __builtin_amdgcn_sched_barrier(0);
            __builtin_amdgcn_s_barrier();
            asm volatile("" ::: "memory");
        }
    }

    // C/D layout: col=lane&15, row=(lane>>4)*4+reg  [m89-verified]
    float* Cp = C + (size_t)lz * plane;
    #pragma unroll
    for (int i = 0; i < 8; ++i) {
        int row = m0 + wm + i * 16 + (lane >> 4) * 4;
        #pragma unroll
        for (int j = 0; j < 4; ++j) {
            int col = n0 + wn + j * 16 + lr;
            #pragma unroll
            for (int rr = 0; rr < 4; ++rr)
                Cp[(size_t)(row + rr) * N + col] = acc[i][j][rr];
        }
    }
    #undef STAGE_A
    #undef STAGE_B
}

// ---------------------------------------------------------------------------
// Fallback fp32 GEMM (round-1 verified, used only if ws_size tiny)
// ---------------------------------------------------------------------------
__global__ __launch_bounds__(256) void kan_gemm(
    const float* __restrict__ X, const float* __restrict__ BW,
    const float* __restrict__ SW, float* __restrict__ Y, int KIN, int OUT)
{
    __shared__ __align__(16) float Asf[72][68];
    __shared__ __align__(16) float Bsf[72][68];
    const int tid = threadIdx.x;
    const int n0 = blockIdx.x * 64;
    const int m0 = blockIdx.y * 64;
    const int tx = tid & 15;
    const int ty = tid >> 4;
    float acc[4][4] = {};
    for (int k0 = 0; k0 < KIN; k0 += 8) {
        #pragma unroll
        for (int rep = 0; rep < 2; ++rep) {
            int idx = rep * 256 + tid;
            int r = idx >> 3, c = idx & 7;
            float x = X[(size_t)(m0 + r) * KIN + k0 + c];
            int bk = c * 9;
            Asf[bk][r] = x;
            #pragma unroll
            for (int z = 0; z < 8; ++z) Asf[bk + 1 + z][r] = 0.0f;
            float xs = (x + 2.2f) * 2.5f;
            float fj = floorf(xs);
            int j = (int)fj;
            if (j >= 0 && j <= 10) {
                float t = xs - fj;
                float t2 = t * t, t3 = t2 * t;
                float omt = 1.0f - t;
                float p0 = omt * omt * omt * (1.0f / 6.0f);
                float p1 = (3.0f * t3 - 6.0f * t2 + 4.0f) * (1.0f / 6.0f);
                float p2 = (-3.0f * t3 + 3.0f * t2 + 3.0f * t + 1.0f) * (1.0f / 6.0f);
                float p3 = t3 * (1.0f / 6.0f);
                if (j >= 3) Asf[bk + 1 + j - 3][r] = p0;
                if (j >= 2 && j <= 9) Asf[bk + 1 + j - 2][r] = p1;
                if (j >= 1 && j <= 8) Asf[bk + 1 + j - 1][r] = p2;
                if (j <= 7) Asf[bk + 1 + j][r] = p3;
            }
        }
        #pragma unroll
        for (int rep = 0; rep < 16; ++rep) {
            int idx = rep * 256 + tid;
            int ol = idx >> 6;
            int l = idx & 63;
            int i = l >> 3, cc = l & 7;
            float v = SW[((size_t)(n0 + ol) * KIN + k0 + i) * 8 + cc];
            Bsf[i * 9 + 1 + cc][ol] = rintf(v * 32.0f) * 0.03125f;
        }
        #pragma unroll
        for (int rep = 0; rep < 2; ++rep) {
            int idx = rep * 256 + tid;
            int ol = idx >> 3, cc = idx & 7;
            Bsf[cc * 9][ol] = BW[(size_t)(n0 + ol) * KIN + k0 + cc];
        }
        __syncthreads();
        #pragma unroll 8
        for (int kk = 0; kk < 72; ++kk) {
            float4 av = *(const float4*)&Asf[kk][ty * 4];
            float4 bv = *(const float4*)&Bsf[kk][tx * 4];
            acc[0][0] += av.x * bv.x; acc[0][1] += av.x * bv.y; acc[0][2] += av.x * bv.z; acc[0][3] += av.x * bv.w;
            acc[1][0] += av.y * bv.x; acc[1][1] += av.y * bv.y; acc[1][2] += av.y * bv.z; acc[1][3] += av.y * bv.w;
            acc[2][0] += av.z * bv.x; acc[2][1] += av.z * bv.y; acc[2][2] += av.z * bv.z; acc[2][3] += av.z * bv.w;
            acc[3][0] += av.w * bv.x; acc[3][1] += av.w * bv.y; acc[3][2] += av.w * bv.z; acc[3][3] += av.w * bv.w;
        }
        __syncthreads();
    }
    #pragma unroll
    for (int i = 0; i < 4; ++i) {
        float4 o = make_float4(acc[i][0], acc[i][1], acc[i][2], acc[i][3]);
        *(float4*)&Y[(size_t)(m0 + ty * 4 + i) * OUT + n0 + tx * 4] = o;
    }
}

// ---------------------------------------------------------------------------
// huxley_rd R13 (R6-verified): PAIRED rows, z = u1 + i*u2; 3 complex FFTs
// per TWO rows. See R6 ledger for exact-split derivation.
// ---------------------------------------------------------------------------
__device__ __forceinline__ float2 block_reduce_sum2(float2 v, float2* red, int tid) {
    red[tid] = v; __syncthreads();
    #pragma unroll
    for (int s = 128; s > 0; s >>= 1) {
        if (tid < s) {
            red[tid].x += red[tid + s].x;
            red[tid].y += red[tid + s].y;
        }
        __syncthreads();
    }
    float2 r = red[0]; __syncthreads();
    return r;
}
__device__ __forceinline__ float2 block_reduce_min2(float2 v, float2* red, int tid) {
    red[tid] = v; __syncthreads();
    #pragma unroll
    for (int s = 128; s > 0; s >>= 1) {
        if (tid < s) {
            red[tid].x = fminf(red[tid].x, red[tid + s].x);
            red[tid].y = fminf(red[tid].y, red[tid + s].y);
        }
        __syncthreads();
    }
    float2 r = red[0]; __syncthreads();
    return r;
}

__device__ void fft1024(float2* X, const float2* tw, int tid, bool inverse) {
    if (!inverse) {
        for (int sh = 9; sh >= 0; --sh) {
            int h = 1 << sh;
            #pragma unroll
            for (int q = 0; q < 2; ++q) {
                int b = tid + q * 256;
                int g = b >> sh, j = b & (h - 1);
                int i0 = (g << (sh + 1)) + j, i1 = i0 + h;
                float2 u = X[i0], v = X[i1];
                float dx = u.x - v.x, dy = u.y - v.y;
                X[i0] = make_float2(u.x + v.x, u.y + v.y);
                float2 w = tw[j << (9 - sh)];
                X[i1] = make_float2(dx * w.x + dy * w.y, dy * w.x - dx * w.y);
            }
            __syncthreads();
        }
    } else {
        for (int sh = 0; sh <= 9; ++sh) {
            int h = 1 << sh;
            #pragma unroll
            for (int q = 0; q < 2; ++q) {
                int b = tid + q * 256;
                int g = b >> sh, j = b & (h - 1);
                int i0 = (g << (sh + 1)) + j, i1 = i0 + h;
                float2 u = X[i0], v = X[i1];
                float2 w = tw[j << (9 - sh)];
                float tx2 = v.x * w.x - v.y * w.y;
                float ty2 = v.x * w.y + v.y * w.x;
                X[i0] = make_float2(u.x + tx2, u.y + ty2);
                X[i1] = make_float2(u.x - tx2, u.y - ty2);
            }
            __syncthreads();
        }
    }
}

__global__ __launch_bounds__(256) void huxley_kernel(
    const float* __restrict__ Pin, size_t plane, int S,
    float* __restrict__ dst,
    const float* __restrict__ sg, const float* __restrict__ dk,
    const float* __restrict__ pa, const float* __restrict__ pgam,
    const float* __restrict__ ptau, const float* __restrict__ pvel,
    const float* __restrict__ gp, const float* __restrict__ chi)
{
    __shared__ float2 A[1024];
    __shared__ float2 Bb[1024];
    __shared__ float2 sErg[1024];
    __shared__ float sAbs1[516];
    __shared__ float sAbs2[516];
    __shared__ float2 tw[512];
    __shared__ float2 red2[256];
    __shared__ float sG[516];

    const int tid = threadIdx.x;
    const int r0 = blockIdx.x * 2;
    const float* pin0 = Pin + (size_t)r0 * 1024;
    const float* pin1 = Pin + (size_t)(r0 + 1) * 1024;
    float* uo0 = dst + (size_t)r0 * 1024;
    float* uo1 = dst + (size_t)(r0 + 1) * 1024;

    for (int m = tid; m < 512; m += 256) {
        float s, c;
        sincosf(6.283185307179586f * (float)m * (1.0f / 1024.0f), &s, &c);
        tw[m] = make_float2(c, s);
    }
    for (int k = tid; k < 513; k += 256)
        sG[k] = 1.0f / (1.0f + expf(-sg[k]));
    for (int i = tid; i < 1024; i += 256) {
        float s0 = 0.0f, s1 = 0.0f;
        for (int ss = 0; ss < S; ++ss) {
            s0 += pin0[(size_t)ss * plane + i];
            s1 += pin1[(size_t)ss * plane + i];
        }
        A[i] = make_float2(s0, s1);   // packed: row1 + i*row2
    }
    __syncthreads();

    fft1024(A, tw, tid, false);       // A = Z (bit-reversed order)

    for (int p = tid; p < 1024; p += 256) {
        int k = (int)(__brev((unsigned)p) >> 22);
        int m = (k <= 512) ? k : 1024 - k;
        float g = sG[m] * (1.0f / 1024.0f);
        Bb[p] = make_float2(A[p].x * g, A[p].y * g);
    }
    __syncthreads();
    fft1024(Bb, tw, tid, true);
    for (int i = tid; i < 1024; i += 256) sErg[i] = Bb[i];
    __syncthreads();

    const float vv = pvel[0];
    for (int p = tid; p < 1024; p += 256) {
        int k = (int)(__brev((unsigned)p) >> 22);
        int m = (k <= 512) ? k : 1024 - k;
        float omg = 1.0f - sG[m];
        float2 z = A[p];
        float nx = z.x * omg, ny = z.y * omg;
        float ang = (k <= 512)
            ? (-6.283185307179586f * vv * (float)k * (1.0f / 1024.0f))
            : (6.283185307179586f * vv * (float)(1024 - k) * (1.0f / 1024.0f));
        float sn, cs;
        sincosf(ang, &sn, &cs);
        float yx, yy;
        if (k == 512) {
            yx = nx * cs;
            yy = ny * cs;
            sAbs1[512] = fabsf(nx * cs);
            sAbs2[512] = fabsf(ny * cs);
        } else {
            yx = nx * cs - ny * sn;
            yy = nx * sn + ny * cs;
            if (k < 512) {
                int p2 = (int)(__brev((unsigned)((1024 - k) & 1023)) >> 22);
                float2 z2 = A[p2];
                float f1x = 0.5f * (z.x + z2.x), f1y = 0.5f * (z.y - z2.y);
                float f2x = 0.5f * (z.y + z2.y), f2y = 0.5f * (z2.x - z.x);
                sAbs1[k] = omg * sqrtf(f1x * f1x + f1y * f1y);
                sAbs2[k] = omg * sqrtf(f2x * f2x + f2y * f2y);
            }
        }
        Bb[p] = make_float2(yx * (1.0f / 1024.0f), yy * (1.0f / 1024.0f));
    }
    __syncthreads();
    fft1024(Bb, tw, tid, true);

    float2 loc = make_float2(0.0f, 0.0f);
    for (int i = tid; i < 1024; i += 256) {
        loc.x += Bb[i].x * Bb[i].x;
        loc.y += Bb[i].y * Bb[i].y;
    }
    float2 trc = block_reduce_sum2(loc, red2, tid);

    loc = make_float2(0.0f, 0.0f);
    for (int k = tid; k < 513; k += 256) { loc.x += sAbs1[k]; loc.y += sAbs2[k]; }
    float2 msum = block_reduce_sum2(loc, red2, tid);
    float2 mean = make_float2(msum.x * (1.0f / 513.0f), msum.y * (1.0f / 513.0f));

    loc = make_float2(0.0f, 0.0f);
    for (int k = tid; k < 513; k += 256) {
        float d1 = sAbs1[k] - mean.x;
        float d2 = sAbs2[k] - mean.y;
        loc.x += d1 * d1; loc.y += d2 * d2;
    }
    float2 varsum = block_reduce_sum2(loc, red2, tid);

    loc = make_float2(3.4e38f, 3.4e38f);
    for (int k = tid; k < 513; k += 256) {
        loc.x = fminf(loc.x, sAbs1[k]);
        loc.y = fminf(loc.y, sAbs2[k]);
    }
    float2 lmin = block_reduce_min2(loc, red2, tid);

    const float tauv = ptau[0];
    float trcv[2]  = { trc.x, trc.y };
    float varv[2]  = { varsum.x, varsum.y };
    float lminv[2] = { lmin.x, lmin.y };
    float gpv[2]   = { gp[r0], gp[r0 + 1] };
    float chv[2]   = { chi[r0], chi[r0 + 1] };
    float cb[2];
    #pragma unroll
    for (int rr = 0; rr < 2; ++rr) {
        float det_pas = varv[rr] * (1.0f / 512.0f) + 1e-6f;
        float sd = sqrtf(det_pas);
        float denom = 2.0f * sd * sd * sd + 1e-8f;
        float c3 = (3.0f * gpv[rr] - trcv[rr] / tauv) / denom;
        c3 = fminf(fmaxf(c3, -0.999f), 0.999f);
        float ph = acosf(c3) * (1.0f / 3.0f);
        float amp = 2.0f * sqrtf(lminv[rr] * (1.0f / 3.0f) + 1e-8f);
        float nu = sqrtf(trcv[rr]);
        float achi = fabsf(chv[rr]);
        float cbest = 0.0f, ebest = -1.0f;
        #pragma unroll
        for (int kb = 0; kb < 3; ++kb) {
            float ck = amp * cosf(ph + 2.0943951023931953f * (float)kb) * expf(-achi * (float)kb);
            float ek = fabsf(ck) * nu;
            if (ek > ebest) { ebest = ek; cbest = ck; }
        }
        cb[rr] = cbest;
    }

    const float a = pa[0], gm = pgam[0];
    const float k0 = dk[0], k1 = dk[1], k2 = dk[2];
    for (int i = tid; i < 1024; i += 256) {
        float2 e = sErg[i];
        float2 l = (i > 0) ? sErg[i - 1] : make_float2(0.0f, 0.0f);
        float2 r = (i < 1023) ? sErg[i + 1] : make_float2(0.0f, 0.0f);
        float reac1 = e.x * (e.x - a) * (1.0f - e.x);
        float diff1 = k0 * l.x + k1 * e.x + k2 * r.x;
        float un1 = e.x + 0.1f * (reac1 + gm * diff1);
        float s1 = un1 + cb[0] * Bb[i].x;
        uo0[i] = s1 / (1.0f + expf(-s1));
        float reac2 = e.y * (e.y - a) * (1.0f - e.y);
        float diff2 = k0 * l.y + k1 * e.y + k2 * r.y;
        float un2 = e.y + 0.1f * (reac2 + gm * diff2);
        float s2 = un2 + cb[1] * Bb[i].y;
        uo1[i] = s2 / (1.0f + expf(-s2));
    }
}

// ---------------------------------------------------------------------------

extern "C" void kernel_launch(void* const* d_in, const int* in_sizes, int n_in,
                              void* d_out, int out_size, void* d_ws, size_t ws_size,
                              hipStream_t stream) {
    const float* c    = (const float*)d_in[0];
    const float* bw0  = (const float*)d_in[1];
    const float* sw0  = (const float*)d_in[2];
    const float* bw1  = (const float*)d_in[3];
    const float* sw1  = (const float*)d_in[4];
    const float* bw2  = (const float*)d_in[5];
    const float* sw2  = (const float*)d_in[6];
    const float* sg   = (const float*)d_in[7];
    const float* dk   = (const float*)d_in[8];
    const float* pa   = (const float*)d_in[9];
    const float* pgam = (const float*)d_in[10];
    const float* ptau = (const float*)d_in[11];
    const float* pvel = (const float*)d_in[12];
    const float* gp   = (const float*)d_in[13];
    const float* chi  = (const float*)d_in[14];

    const int B = 4096, NIN = 512, W = 1024, NOUT = 1024;
    const int KE0 = 19 * NIN, KE1 = 19 * W;
    const size_t MN = (size_t)B * W;
    const size_t BE = (size_t)W * KE1 * 2;      // Bexp bytes (39.85 MB)
    dim3 blk(256);
    dim3 gblk(512);

    // ---- pick (CH, S): 256-row m-tiles; {4096,4} -> gemm grid 4x16x4 = 256 ----
    struct Cand { int CH, S; };
    const Cand cands[] = {
        {4096, 4}, {4096, 3}, {2048, 4}, {2048, 3}, {1024, 4},
        {512, 4}, {256, 4}
    };
    int CH = 0, S = 1;
    for (const auto& cd : cands) {
        size_t need = BE + (size_t)cd.CH * KE1 * 2 + (size_t)cd.S * MN * 4;
        if (need <= ws_size) { CH = cd.CH; S = cd.S; break; }
    }

    if (CH > 0) {
        f16* Bexp = (f16*)d_ws;
        float* P  = (float*)((char*)d_ws + BE);                // S planes of M x N fp32
        f16* Aexp = (f16*)((char*)d_ws + BE + (size_t)S * MN * 4);

        // ceil-split Kc (multiple of 64 for BK=64; KE0/KE1 are 64-multiples)
        const int Kc0 = ((KE0 / 64 + S - 1) / S) * 64;
        const int Kc1 = ((KE1 / 64 + S - 1) / S) * 64;

        // ---- layer 0: KIN=512 ----
        prep_b<<<(W * NIN) / 256, blk, 0, stream>>>(bw0, sw0, Bexp, NIN, 9);
        for (int r0 = 0; r0 < B; r0 += CH) {
            expand_sum_a<<<(CH * NIN) / 256, blk, 0, stream>>>(
                c + (size_t)r0 * NIN, 0, 1, Aexp, NIN, 9);
            gemm_mfma<<<dim3(W / 256, CH / 256, S), gblk, 0, stream>>>(
                Aexp, Bexp, P + (size_t)r0 * W, KE0, Kc0, MN, W);
        }
        // ---- layer 1: KIN=1024 ----
        prep_b<<<(W * W) / 256, blk, 0, stream>>>(bw1, sw1, Bexp, W, 10);
        for (int r0 = 0; r0 < B; r0 += CH) {
            expand_sum_a<<<(CH * W) / 256, blk, 0, stream>>>(
                P + (size_t)r0 * W, MN, S, Aexp, W, 10);
            gemm_mfma<<<dim3(W / 256, CH / 256, S), gblk, 0, stream>>>(
                Aexp, Bexp, P + (size_t)r0 * W, KE1, Kc1, MN, W);
        }
        // ---- layer 2 ----
        prep_b<<<(NOUT * W) / 256, blk, 0, stream>>>(bw2, sw2, Bexp, W, 10);
        for (int r0 = 0; r0 < B; r0 += CH) {
            expand_sum_a<<<(CH * W) / 256, blk, 0, stream>>>(
                P + (size_t)r0 * W, MN, S, Aexp, W, 10);
            gemm_mfma<<<dim3(NOUT / 256, CH / 256, S), gblk, 0, stream>>>(
                Aexp, Bexp, P + (size_t)r0 * W, KE1, Kc1, MN, NOUT);
        }
        huxley_kernel<<<B / 2, blk, 0, stream>>>(P, MN, S, (float*)d_out,
                                                 sg, dk, pa, pgam, ptau, pvel, gp, chi);
    } else {
        // fallback: round-1 fp32 path (needs only 33.6 MB ws)
        float* fx0 = (float*)d_ws;
        float* fx1 = fx0 + (size_t)B * W;
        dim3 g0(W / 64, B / 64);
        kan_gemm<<<g0, blk, 0, stream>>>(c,   bw0, sw0, fx0, NIN, W);
        kan_gemm<<<g0, blk, 0, stream>>>(fx0, bw1, sw1, fx1, W,   W);
        dim3 g2(NOUT / 64, B / 64);
        kan_gemm<<<g2, blk, 0, stream>>>(fx1, bw2, sw2, (float*)d_out, W, NOUT);
        huxley_kernel<<<B / 2, blk, 0, stream>>>((float*)d_out, 0, 1, (float*)d_out,
                                                 sg, dk, pa, pgam, ptau, pvel, gp, chi);
    }
}

// Round 11
// 665.604 us; speedup vs baseline: 1.2011x; 1.0236x over previous
//
#include <hip/hip_runtime.h>
#include <math.h>

typedef _Float16 f16;
typedef _Float16 f16x8 __attribute__((ext_vector_type(8)));
typedef float f32x4 __attribute__((ext_vector_type(4)));

// ---------------------------------------------------------------------------
// expand_sum_a: x[b,i] = sum_{s<Sin} src[s*plane + b*KIN + i]  (Sin=1: raw input)
// -> Aexp (rows x KIN*19 fp16)
// planes per row: [0,8K): basis-hi | [8K,16K): basis-lo | xh | xh | xl
// ---------------------------------------------------------------------------
__global__ __launch_bounds__(256) void expand_sum_a(
    const float* __restrict__ src, size_t plane, int Sin,
    f16* __restrict__ Aexp, int KIN, int shift)
{
    int idx = blockIdx.x * 256 + threadIdx.x;
    int i = idx & (KIN - 1);
    int b = idx >> shift;
    float x = 0.0f;
    for (int s = 0; s < Sin; ++s) x += src[(size_t)s * plane + idx];

    float xs = (x + 2.2f) * 2.5f;
    float fj = floorf(xs);
    int jj = (int)fj;
    float t = xs - fj;
    float t2 = t * t, t3 = t2 * t;
    float omt = 1.0f - t;
    float p0 = omt * omt * omt * (1.0f / 6.0f);
    float p1 = (3.0f * t3 - 6.0f * t2 + 4.0f) * (1.0f / 6.0f);
    float p2 = (-3.0f * t3 + 3.0f * t2 + 3.0f * t + 1.0f) * (1.0f / 6.0f);
    float p3 = t3 * (1.0f / 6.0f);

    union { f16 h[8]; uint4 v; } hi, lo;
    bool inr = (jj >= 0 && jj <= 10);
    #pragma unroll
    for (int cc = 0; cc < 8; ++cc) {
        int d = cc - (jj - 3);
        float v = 0.0f;
        if (inr) {
            if (d == 0) v = p0; else if (d == 1) v = p1;
            else if (d == 2) v = p2; else if (d == 3) v = p3;
        }
        f16 h = (f16)v;
        hi.h[cc] = h;
        lo.h[cc] = (f16)(v - (float)h);
    }
    size_t KEXP = (size_t)KIN * 19;
    f16* row = Aexp + (size_t)b * KEXP;
    *(uint4*)(row + (size_t)i * 8) = hi.v;
    *(uint4*)(row + (size_t)KIN * 8 + (size_t)i * 8) = lo.v;
    f16 xh = (f16)x;
    f16 xl = (f16)(x - (float)xh);
    int K16 = KIN * 16;
    row[K16 + i] = xh;
    row[K16 + KIN + i] = xh;
    row[K16 + 2 * KIN + i] = xl;
}

// ---------------------------------------------------------------------------
// prep_b (round-3 verified): planes [qw x8][qw x8][wh][wl][wh]
// pairing with A: (bh+bl)*qw + xh*wh + xh*wl + xl*wh
// ---------------------------------------------------------------------------
__global__ __launch_bounds__(256) void prep_b(
    const float* __restrict__ BW, const float* __restrict__ SW,
    f16* __restrict__ Bexp, int KIN, int shift)
{
    int idx = blockIdx.x * 256 + threadIdx.x;
    int i = idx & (KIN - 1);
    int o = idx >> shift;
    const float* sp = SW + ((size_t)o * KIN + i) * 8;
    union { f16 h[8]; uint4 v; } pk;
    #pragma unroll
    for (int cc = 0; cc < 8; ++cc)
        pk.h[cc] = (f16)(rintf(sp[cc] * 32.0f) * 0.03125f);  // n/32, exact in fp16
    size_t KEXP = (size_t)KIN * 19;
    f16* row = Bexp + (size_t)o * KEXP;
    *(uint4*)(row + (size_t)i * 8) = pk.v;
    *(uint4*)(row + (size_t)KIN * 8 + (size_t)i * 8) = pk.v;
    float w = BW[(size_t)o * KIN + i];
    f16 wh = (f16)w;
    f16 wl = (f16)(w - (float)wh);
    int K16 = KIN * 16;
    row[K16 + i] = wh;
    row[K16 + KIN + i] = wl;
    row[K16 + 2 * KIN + i] = wh;
}

// ---------------------------------------------------------------------------
// gemm_mfma (ring-4, R3-verified best, 47.6% MfmaUtil): used when S<=4.
// 256x256 tile, 512 thr / 8 waves (2Mx4N), wave tile 128x64, 4-slot BK=32
// ring, prefetch 3, ONE barrier/K-tile, counted vmcnt 8/4/0 + lgkm 4/0.
// XOR bank-swizzle + XCD-bijective block swizzle (see R3 ledger).
// Session ledger: schedule families measured -- 4-barrier 43.3%, THIS 47.6%,
// mid-barrier 43.5%, BK=64 coarse 43.7%, 128^2 4-blk/CU 33%, m201-quadrant
// 42% -- this structure is the measured optimum for this operand shape.
// ---------------------------------------------------------------------------
__global__ __launch_bounds__(512, 2) void gemm_mfma(
    const f16* __restrict__ A, const f16* __restrict__ Bm,
    float* __restrict__ C, int Kfull, int Kc, size_t plane, int N)
{
    __shared__ __align__(16) f16 As[4][8192];
    __shared__ __align__(16) f16 Bs[4][8192];

    const int tid = threadIdx.x;
    const int wave = tid >> 6, lane = tid & 63;

    const int nwg = gridDim.x * gridDim.y * gridDim.z;
    const int b = blockIdx.x + gridDim.x * (blockIdx.y + gridDim.y * blockIdx.z);
    const int q = nwg >> 3;
    const int L = (b & 7) * q + (b >> 3);
    const int lx = L % gridDim.x;
    const int rest = L / gridDim.x;
    const int ly = rest % gridDim.y;
    const int lz = rest / gridDim.y;

    const int m0 = ly * 256, n0 = lx * 256;
    const int kb = lz * Kc;
    int kcl = Kfull - kb; if (kcl > Kc) kcl = Kc;
    const int NT = kcl >> 5;

    const int kc_src = (lane & 3) ^ ((lane >> 3) & 3);
    const f16* gb[4];
    int isA_[4], coff[4];
    #pragma unroll
    for (int j = 0; j < 4; ++j) {
        int cch = wave * 4 + j;
        int a = (cch < 16);
        int c8 = a ? cch : (cch - 16);
        int row0 = (a ? m0 : n0) + c8 * 16 + (lane >> 2);
        gb[j] = (a ? A : Bm) + (size_t)row0 * Kfull + kb + kc_src * 8;
        isA_[j] = a;
        coff[j] = c8 * 512;
    }

    f32x4 acc[8][4];
    #pragma unroll
    for (int i = 0; i < 8; ++i)
        #pragma unroll
        for (int j = 0; j < 4; ++j)
            acc[i][j] = (f32x4){0.f, 0.f, 0.f, 0.f};

    #pragma unroll
    for (int s = 0; s < 3; ++s) {
        if (s < NT) {
            int k0 = s << 5;
            #pragma unroll
            for (int j = 0; j < 4; ++j) {
                f16* dp = isA_[j] ? &As[s][coff[j]] : &Bs[s][coff[j]];
                __builtin_amdgcn_global_load_lds(
                    (const __attribute__((address_space(1))) unsigned int*)(gb[j] + k0),
                    (__attribute__((address_space(3))) unsigned int*)dp, 16, 0, 0);
            }
        }
    }
    if (NT >= 3)      asm volatile("s_waitcnt vmcnt(8)" ::: "memory");
    else if (NT == 2) asm volatile("s_waitcnt vmcnt(4)" ::: "memory");
    else              asm volatile("s_waitcnt vmcnt(0)" ::: "memory");
    __builtin_amdgcn_s_barrier();
    asm volatile("" ::: "memory");

    const int lr = lane & 15;
    const int ko = (((lane >> 4) ^ ((lr >> 1) & 3)) & 3) * 8;
    const int wm = (wave & 1) * 128, wn = (wave >> 1) * 64;

    for (int t = 0; t < NT; ++t) {
        const int st = t & 3;
        const int ns = (t + 3) & 3;
        const bool pf = (t + 3 < NT);
        const int kn = (t + 3) << 5;
        const int rem = NT - 1 - t;

        f16x8 af[4], bf[4], ag[4];
        #pragma unroll
        for (int i = 0; i < 4; ++i)
            af[i] = *(const f16x8*)&As[st][(wm + i * 16 + lr) * 32 + ko];
        #pragma unroll
        for (int j = 0; j < 4; ++j)
            bf[j] = *(const f16x8*)&Bs[st][(wn + j * 16 + lr) * 32 + ko];
        if (pf) {
            #pragma unroll
            for (int j = 0; j < 2; ++j) {
                f16* dp = isA_[j] ? &As[ns][coff[j]] : &Bs[ns][coff[j]];
                __builtin_amdgcn_global_load_lds(
                    (const __attribute__((address_space(1))) unsigned int*)(gb[j] + kn),
                    (__attribute__((address_space(3))) unsigned int*)dp, 16, 0, 0);
            }
        }
        #pragma unroll
        for (int i = 0; i < 4; ++i)
            ag[i] = *(const f16x8*)&As[st][(wm + 64 + i * 16 + lr) * 32 + ko];
        if (pf) {
            #pragma unroll
            for (int j = 2; j < 4; ++j) {
                f16* dp = isA_[j] ? &As[ns][coff[j]] : &Bs[ns][coff[j]];
                __builtin_amdgcn_global_load_lds(
                    (const __attribute__((address_space(1))) unsigned int*)(gb[j] + kn),
                    (__attribute__((address_space(3))) unsigned int*)dp, 16, 0, 0);
            }
        }

        asm volatile("s_waitcnt lgkmcnt(4)" ::: "memory");
        __builtin_amdgcn_sched_barrier(0);
        __builtin_amdgcn_s_setprio(1);
        #pragma unroll
        for (int i = 0; i < 4; ++i)
            #pragma unroll
            for (int j = 0; j < 4; ++j)
                acc[i][j] = __builtin_amdgcn_mfma_f32_16x16x32_f16(af[i], bf[j], acc[i][j], 0, 0, 0);
        __builtin_amdgcn_s_setprio(0);

        asm volatile("s_waitcnt lgkmcnt(0)" ::: "memory");
        __builtin_amdgcn_sched_barrier(0);
        __builtin_amdgcn_s_setprio(1);
        #pragma unroll
        for (int i = 0; i < 4; ++i)
            #pragma unroll
            for (int j = 0; j < 4; ++j)
                acc[4 + i][j] = __builtin_amdgcn_mfma_f32_16x16x32_f16(ag[i], bf[j], acc[4 + i][j], 0, 0, 0);
        __builtin_amdgcn_s_setprio(0);

        if (rem >= 3)      asm volatile("s_waitcnt vmcnt(8)" ::: "memory");
        else if (rem == 2) asm volatile("s_waitcnt vmcnt(4)" ::: "memory");
        else if (rem == 1) asm volatile("s_waitcnt vmcnt(0)" ::: "memory");
        if (rem >= 1) {
            __builtin_amdgcn_sched_barrier(0);
            __builtin_amdgcn_s_barrier();
            asm volatile("" ::: "memory");
        }
    }

    float* Cp = C + (size_t)lz * plane;
    #pragma unroll
    for (int i = 0; i < 8; ++i) {
        int row = m0 + wm + i * 16 + (lane >> 4) * 4;
        #pragma unroll
        for (int j = 0; j < 4; ++j) {
            int col = n0 + wn + j * 16 + lr;
            #pragma unroll
            for (int rr = 0; rr < 4; ++rr)
                Cp[(size_t)(row + rr) * N + col] = acc[i][j][rr];
        }
    }
}

// ---------------------------------------------------------------------------
// gemm_mfma2 (ring-2, 64KB LDS): used only when S==8 fits ws (inert at
// current ws_size; kept for larger-workspace environments).
// ---------------------------------------------------------------------------
__global__ __launch_bounds__(512, 4) void gemm_mfma2(
    const f16* __restrict__ A, const f16* __restrict__ Bm,
    float* __restrict__ C, int Kfull, int Kc, size_t plane, int N)
{
    __shared__ __align__(16) f16 As[2][8192];
    __shared__ __align__(16) f16 Bs[2][8192];

    const int tid = threadIdx.x;
    const int wave = tid >> 6, lane = tid & 63;

    const int nwg = gridDim.x * gridDim.y * gridDim.z;
    const int b = blockIdx.x + gridDim.x * (blockIdx.y + gridDim.y * blockIdx.z);
    const int q = nwg >> 3;
    const int L = (b & 7) * q + (b >> 3);
    const int lx = L % gridDim.x;
    const int rest = L / gridDim.x;
    const int ly = rest % gridDim.y;
    const int lz = rest / gridDim.y;

    const int m0 = ly * 256, n0 = lx * 256;
    const int kb = lz * Kc;
    int kcl = Kfull - kb; if (kcl > Kc) kcl = Kc;
    const int NT = kcl >> 5;

    const int kc_src = (lane & 3) ^ ((lane >> 3) & 3);
    const f16* gb[4];
    int isA_[4], coff[4];
    #pragma unroll
    for (int j = 0; j < 4; ++j) {
        int cch = wave * 4 + j;
        int a = (cch < 16);
        int c8 = a ? cch : (cch - 16);
        int row0 = (a ? m0 : n0) + c8 * 16 + (lane >> 2);
        gb[j] = (a ? A : Bm) + (size_t)row0 * Kfull + kb + kc_src * 8;
        isA_[j] = a;
        coff[j] = c8 * 512;
    }

    f32x4 acc[8][4];
    #pragma unroll
    for (int i = 0; i < 8; ++i)
        #pragma unroll
        for (int j = 0; j < 4; ++j)
            acc[i][j] = (f32x4){0.f, 0.f, 0.f, 0.f};

    #pragma unroll
    for (int j = 0; j < 4; ++j) {
        f16* dp = isA_[j] ? &As[0][coff[j]] : &Bs[0][coff[j]];
        __builtin_amdgcn_global_load_lds(
            (const __attribute__((address_space(1))) unsigned int*)(gb[j]),
            (__attribute__((address_space(3))) unsigned int*)dp, 16, 0, 0);
    }
    asm volatile("s_waitcnt vmcnt(0)" ::: "memory");
    __builtin_amdgcn_s_barrier();
    asm volatile("" ::: "memory");

    const int lr = lane & 15;
    const int ko = (((lane >> 4) ^ ((lr >> 1) & 3)) & 3) * 8;
    const int wm = (wave & 1) * 128, wn = (wave >> 1) * 64;

    for (int t = 0; t < NT; ++t) {
        const int st = t & 1;
        const int ns = st ^ 1;
        const bool pf = (t + 1 < NT);
        const int kn = (t + 1) << 5;

        f16x8 af[4], bf[4], ag[4];
        #pragma unroll
        for (int i = 0; i < 4; ++i)
            af[i] = *(const f16x8*)&As[st][(wm + i * 16 + lr) * 32 + ko];
        #pragma unroll
        for (int j = 0; j < 4; ++j)
            bf[j] = *(const f16x8*)&Bs[st][(wn + j * 16 + lr) * 32 + ko];
        if (pf) {
            #pragma unroll
            for (int j = 0; j < 2; ++j) {
                f16* dp = isA_[j] ? &As[ns][coff[j]] : &Bs[ns][coff[j]];
                __builtin_amdgcn_global_load_lds(
                    (const __attribute__((address_space(1))) unsigned int*)(gb[j] + kn),
                    (__attribute__((address_space(3))) unsigned int*)dp, 16, 0, 0);
            }
        }
        #pragma unroll
        for (int i = 0; i < 4; ++i)
            ag[i] = *(const f16x8*)&As[st][(wm + 64 + i * 16 + lr) * 32 + ko];
        if (pf) {
            #pragma unroll
            for (int j = 2; j < 4; ++j) {
                f16* dp = isA_[j] ? &As[ns][coff[j]] : &Bs[ns][coff[j]];
                __builtin_amdgcn_global_load_lds(
                    (const __attribute__((address_space(1))) unsigned int*)(gb[j] + kn),
                    (__attribute__((address_space(3))) unsigned int*)dp, 16, 0, 0);
            }
        }

        asm volatile("s_waitcnt lgkmcnt(4)" ::: "memory");
        __builtin_amdgcn_sched_barrier(0);
        __builtin_amdgcn_s_setprio(1);
        #pragma unroll
        for (int i = 0; i < 4; ++i)
            #pragma unroll
            for (int j = 0; j < 4; ++j)
                acc[i][j] = __builtin_amdgcn_mfma_f32_16x16x32_f16(af[i], bf[j], acc[i][j], 0, 0, 0);
        __builtin_amdgcn_s_setprio(0);

        asm volatile("s_waitcnt lgkmcnt(0)" ::: "memory");
        __builtin_amdgcn_sched_barrier(0);
        __builtin_amdgcn_s_setprio(1);
        #pragma unroll
        for (int i = 0; i < 4; ++i)
            #pragma unroll
            for (int j = 0; j < 4; ++j)
                acc[4 + i][j] = __builtin_amdgcn_mfma_f32_16x16x32_f16(ag[i], bf[j], acc[4 + i][j], 0, 0, 0);
        __builtin_amdgcn_s_setprio(0);

        if (pf) {
            asm volatile("s_waitcnt vmcnt(0)" ::: "memory");
            __builtin_amdgcn_sched_barrier(0);
            __builtin_amdgcn_s_barrier();
            asm volatile("" ::: "memory");
        }
    }

    float* Cp = C + (size_t)lz * plane;
    #pragma unroll
    for (int i = 0; i < 8; ++i) {
        int row = m0 + wm + i * 16 + (lane >> 4) * 4;
        #pragma unroll
        for (int j = 0; j < 4; ++j) {
            int col = n0 + wn + j * 16 + lr;
            #pragma unroll
            for (int rr = 0; rr < 4; ++rr)
                Cp[(size_t)(row + rr) * N + col] = acc[i][j][rr];
        }
    }
}

// ---------------------------------------------------------------------------
// Fallback fp32 GEMM (round-1 verified, used only if ws_size tiny)
// ---------------------------------------------------------------------------
__global__ __launch_bounds__(256) void kan_gemm(
    const float* __restrict__ X, const float* __restrict__ BW,
    const float* __restrict__ SW, float* __restrict__ Y, int KIN, int OUT)
{
    __shared__ __align__(16) float Asf[72][68];
    __shared__ __align__(16) float Bsf[72][68];
    const int tid = threadIdx.x;
    const int n0 = blockIdx.x * 64;
    const int m0 = blockIdx.y * 64;
    const int tx = tid & 15;
    const int ty = tid >> 4;
    float acc[4][4] = {};
    for (int k0 = 0; k0 < KIN; k0 += 8) {
        #pragma unroll
        for (int rep = 0; rep < 2; ++rep) {
            int idx = rep * 256 + tid;
            int r = idx >> 3, c = idx & 7;
            float x = X[(size_t)(m0 + r) * KIN + k0 + c];
            int bk = c * 9;
            Asf[bk][r] = x;
            #pragma unroll
            for (int z = 0; z < 8; ++z) Asf[bk + 1 + z][r] = 0.0f;
            float xs = (x + 2.2f) * 2.5f;
            float fj = floorf(xs);
            int j = (int)fj;
            if (j >= 0 && j <= 10) {
                float t = xs - fj;
                float t2 = t * t, t3 = t2 * t;
                float omt = 1.0f - t;
                float p0 = omt * omt * omt * (1.0f / 6.0f);
                float p1 = (3.0f * t3 - 6.0f * t2 + 4.0f) * (1.0f / 6.0f);
                float p2 = (-3.0f * t3 + 3.0f * t2 + 3.0f * t + 1.0f) * (1.0f / 6.0f);
                float p3 = t3 * (1.0f / 6.0f);
                if (j >= 3) Asf[bk + 1 + j - 3][r] = p0;
                if (j >= 2 && j <= 9) Asf[bk + 1 + j - 2][r] = p1;
                if (j >= 1 && j <= 8) Asf[bk + 1 + j - 1][r] = p2;
                if (j <= 7) Asf[bk + 1 + j][r] = p3;
            }
        }
        #pragma unroll
        for (int rep = 0; rep < 16; ++rep) {
            int idx = rep * 256 + tid;
            int ol = idx >> 6;
            int l = idx & 63;
            int i = l >> 3, cc = l & 7;
            float v = SW[((size_t)(n0 + ol) * KIN + k0 + i) * 8 + cc];
            Bsf[i * 9 + 1 + cc][ol] = rintf(v * 32.0f) * 0.03125f;
        }
        #pragma unroll
        for (int rep = 0; rep < 2; ++rep) {
            int idx = rep * 256 + tid;
            int ol = idx >> 3, cc = idx & 7;
            Bsf[cc * 9][ol] = BW[(size_t)(n0 + ol) * KIN + k0 + cc];
        }
        __syncthreads();
        #pragma unroll 8
        for (int kk = 0; kk < 72; ++kk) {
            float4 av = *(const float4*)&Asf[kk][ty * 4];
            float4 bv = *(const float4*)&Bsf[kk][tx * 4];
            acc[0][0] += av.x * bv.x; acc[0][1] += av.x * bv.y; acc[0][2] += av.x * bv.z; acc[0][3] += av.x * bv.w;
            acc[1][0] += av.y * bv.x; acc[1][1] += av.y * bv.y; acc[1][2] += av.y * bv.z; acc[1][3] += av.y * bv.w;
            acc[2][0] += av.z * bv.x; acc[2][1] += av.z * bv.y; acc[2][2] += av.z * bv.z; acc[2][3] += av.z * bv.w;
            acc[3][0] += av.w * bv.x; acc[3][1] += av.w * bv.y; acc[3][2] += av.w * bv.z; acc[3][3] += av.w * bv.w;
        }
        __syncthreads();
    }
    #pragma unroll
    for (int i = 0; i < 4; ++i) {
        float4 o = make_float4(acc[i][0], acc[i][1], acc[i][2], acc[i][3]);
        *(float4*)&Y[(size_t)(m0 + ty * 4 + i) * OUT + n0 + tx * 4] = o;
    }
}

// ---------------------------------------------------------------------------
// huxley_rd R13 (R6-verified): PAIRED rows, z = u1 + i*u2; 3 complex FFTs
// per TWO rows. See R6 ledger for exact-split derivation (gate real-even,
// phase conj-symmetric, bin-512 cos-only, sAbs via F1/F2 separation).
// ---------------------------------------------------------------------------
__device__ __forceinline__ float2 block_reduce_sum2(float2 v, float2* red, int tid) {
    red[tid] = v; __syncthreads();
    #pragma unroll
    for (int s = 128; s > 0; s >>= 1) {
        if (tid < s) {
            red[tid].x += red[tid + s].x;
            red[tid].y += red[tid + s].y;
        }
        __syncthreads();
    }
    float2 r = red[0]; __syncthreads();
    return r;
}
__device__ __forceinline__ float2 block_reduce_min2(float2 v, float2* red, int tid) {
    red[tid] = v; __syncthreads();
    #pragma unroll
    for (int s = 128; s > 0; s >>= 1) {
        if (tid < s) {
            red[tid].x = fminf(red[tid].x, red[tid + s].x);
            red[tid].y = fminf(red[tid].y, red[tid + s].y);
        }
        __syncthreads();
    }
    float2 r = red[0]; __syncthreads();
    return r;
}

__device__ void fft1024(float2* X, const float2* tw, int tid, bool inverse) {
    if (!inverse) {
        for (int sh = 9; sh >= 0; --sh) {
            int h = 1 << sh;
            #pragma unroll
            for (int q = 0; q < 2; ++q) {
                int b = tid + q * 256;
                int g = b >> sh, j = b & (h - 1);
                int i0 = (g << (sh + 1)) + j, i1 = i0 + h;
                float2 u = X[i0], v = X[i1];
                float dx = u.x - v.x, dy = u.y - v.y;
                X[i0] = make_float2(u.x + v.x, u.y + v.y);
                float2 w = tw[j << (9 - sh)];
                X[i1] = make_float2(dx * w.x + dy * w.y, dy * w.x - dx * w.y);
            }
            __syncthreads();
        }
    } else {
        for (int sh = 0; sh <= 9; ++sh) {
            int h = 1 << sh;
            #pragma unroll
            for (int q = 0; q < 2; ++q) {
                int b = tid + q * 256;
                int g = b >> sh, j = b & (h - 1);
                int i0 = (g << (sh + 1)) + j, i1 = i0 + h;
                float2 u = X[i0], v = X[i1];
                float2 w = tw[j << (9 - sh)];
                float tx2 = v.x * w.x - v.y * w.y;
                float ty2 = v.x * w.y + v.y * w.x;
                X[i0] = make_float2(u.x + tx2, u.y + ty2);
                X[i1] = make_float2(u.x - tx2, u.y - ty2);
            }
            __syncthreads();
        }
    }
}

__global__ __launch_bounds__(256) void huxley_kernel(
    const float* __restrict__ Pin, size_t plane, int S,
    float* __restrict__ dst,
    const float* __restrict__ sg, const float* __restrict__ dk,
    const float* __restrict__ pa, const float* __restrict__ pgam,
    const float* __restrict__ ptau, const float* __restrict__ pvel,
    const float* __restrict__ gp, const float* __restrict__ chi)
{
    __shared__ float2 A[1024];
    __shared__ float2 Bb[1024];
    __shared__ float2 sErg[1024];
    __shared__ float sAbs1[516];
    __shared__ float sAbs2[516];
    __shared__ float2 tw[512];
    __shared__ float2 red2[256];
    __shared__ float sG[516];

    const int tid = threadIdx.x;
    const int r0 = blockIdx.x * 2;
    const float* pin0 = Pin + (size_t)r0 * 1024;
    const float* pin1 = Pin + (size_t)(r0 + 1) * 1024;
    float* uo0 = dst + (size_t)r0 * 1024;
    float* uo1 = dst + (size_t)(r0 + 1) * 1024;

    for (int m = tid; m < 512; m += 256) {
        float s, c;
        sincosf(6.283185307179586f * (float)m * (1.0f / 1024.0f), &s, &c);
        tw[m] = make_float2(c, s);
    }
    for (int k = tid; k < 513; k += 256)
        sG[k] = 1.0f / (1.0f + expf(-sg[k]));
    for (int i = tid; i < 1024; i += 256) {
        float s0 = 0.0f, s1 = 0.0f;
        for (int ss = 0; ss < S; ++ss) {
            s0 += pin0[(size_t)ss * plane + i];
            s1 += pin1[(size_t)ss * plane + i];
        }
        A[i] = make_float2(s0, s1);   // packed: row1 + i*row2
    }
    __syncthreads();

    fft1024(A, tw, tid, false);       // A = Z (bit-reversed order)

    for (int p = tid; p < 1024; p += 256) {
        int k = (int)(__brev((unsigned)p) >> 22);
        int m = (k <= 512) ? k : 1024 - k;
        float g = sG[m] * (1.0f / 1024.0f);
        Bb[p] = make_float2(A[p].x * g, A[p].y * g);
    }
    __syncthreads();
    fft1024(Bb, tw, tid, true);
    for (int i = tid; i < 1024; i += 256) sErg[i] = Bb[i];
    __syncthreads();

    const float vv = pvel[0];
    for (int p = tid; p < 1024; p += 256) {
        int k = (int)(__brev((unsigned)p) >> 22);
        int m = (k <= 512) ? k : 1024 - k;
        float omg = 1.0f - sG[m];
        float2 z = A[p];
        float nx = z.x * omg, ny = z.y * omg;
        float ang = (k <= 512)
            ? (-6.283185307179586f * vv * (float)k * (1.0f / 1024.0f))
            : (6.283185307179586f * vv * (float)(1024 - k) * (1.0f / 1024.0f));
        float sn, cs;
        sincosf(ang, &sn, &cs);
        float yx, yy;
        if (k == 512) {
            yx = nx * cs;
            yy = ny * cs;
            sAbs1[512] = fabsf(nx * cs);
            sAbs2[512] = fabsf(ny * cs);
        } else {
            yx = nx * cs - ny * sn;
            yy = nx * sn + ny * cs;
            if (k < 512) {
                int p2 = (int)(__brev((unsigned)((1024 - k) & 1023)) >> 22);
                float2 z2 = A[p2];
                float f1x = 0.5f * (z.x + z2.x), f1y = 0.5f * (z.y - z2.y);
                float f2x = 0.5f * (z.y + z2.y), f2y = 0.5f * (z2.x - z.x);
                sAbs1[k] = omg * sqrtf(f1x * f1x + f1y * f1y);
                sAbs2[k] = omg * sqrtf(f2x * f2x + f2y * f2y);
            }
        }
        Bb[p] = make_float2(yx * (1.0f / 1024.0f), yy * (1.0f / 1024.0f));
    }
    __syncthreads();
    fft1024(Bb, tw, tid, true);

    float2 loc = make_float2(0.0f, 0.0f);
    for (int i = tid; i < 1024; i += 256) {
        loc.x += Bb[i].x * Bb[i].x;
        loc.y += Bb[i].y * Bb[i].y;
    }
    float2 trc = block_reduce_sum2(loc, red2, tid);

    loc = make_float2(0.0f, 0.0f);
    for (int k = tid; k < 513; k += 256) { loc.x += sAbs1[k]; loc.y += sAbs2[k]; }
    float2 msum = block_reduce_sum2(loc, red2, tid);
    float2 mean = make_float2(msum.x * (1.0f / 513.0f), msum.y * (1.0f / 513.0f));

    loc = make_float2(0.0f, 0.0f);
    for (int k = tid; k < 513; k += 256) {
        float d1 = sAbs1[k] - mean.x;
        float d2 = sAbs2[k] - mean.y;
        loc.x += d1 * d1; loc.y += d2 * d2;
    }
    float2 varsum = block_reduce_sum2(loc, red2, tid);

    loc = make_float2(3.4e38f, 3.4e38f);
    for (int k = tid; k < 513; k += 256) {
        loc.x = fminf(loc.x, sAbs1[k]);
        loc.y = fminf(loc.y, sAbs2[k]);
    }
    float2 lmin = block_reduce_min2(loc, red2, tid);

    const float tauv = ptau[0];
    float trcv[2]  = { trc.x, trc.y };
    float varv[2]  = { varsum.x, varsum.y };
    float lminv[2] = { lmin.x, lmin.y };
    float gpv[2]   = { gp[r0], gp[r0 + 1] };
    float chv[2]   = { chi[r0], chi[r0 + 1] };
    float cb[2];
    #pragma unroll
    for (int rr = 0; rr < 2; ++rr) {
        float det_pas = varv[rr] * (1.0f / 512.0f) + 1e-6f;
        float sd = sqrtf(det_pas);
        float denom = 2.0f * sd * sd * sd + 1e-8f;
        float c3 = (3.0f * gpv[rr] - trcv[rr] / tauv) / denom;
        c3 = fminf(fmaxf(c3, -0.999f), 0.999f);
        float ph = acosf(c3) * (1.0f / 3.0f);
        float amp = 2.0f * sqrtf(lminv[rr] * (1.0f / 3.0f) + 1e-8f);
        float nu = sqrtf(trcv[rr]);
        float achi = fabsf(chv[rr]);
        float cbest = 0.0f, ebest = -1.0f;
        #pragma unroll
        for (int kb = 0; kb < 3; ++kb) {
            float ck = amp * cosf(ph + 2.0943951023931953f * (float)kb) * expf(-achi * (float)kb);
            float ek = fabsf(ck) * nu;
            if (ek > ebest) { ebest = ek; cbest = ck; }
        }
        cb[rr] = cbest;
    }

    const float a = pa[0], gm = pgam[0];
    const float k0 = dk[0], k1 = dk[1], k2 = dk[2];
    for (int i = tid; i < 1024; i += 256) {
        float2 e = sErg[i];
        float2 l = (i > 0) ? sErg[i - 1] : make_float2(0.0f, 0.0f);
        float2 r = (i < 1023) ? sErg[i + 1] : make_float2(0.0f, 0.0f);
        float reac1 = e.x * (e.x - a) * (1.0f - e.x);
        float diff1 = k0 * l.x + k1 * e.x + k2 * r.x;
        float un1 = e.x + 0.1f * (reac1 + gm * diff1);
        float s1 = un1 + cb[0] * Bb[i].x;
        uo0[i] = s1 / (1.0f + expf(-s1));
        float reac2 = e.y * (e.y - a) * (1.0f - e.y);
        float diff2 = k0 * l.y + k1 * e.y + k2 * r.y;
        float un2 = e.y + 0.1f * (reac2 + gm * diff2);
        float s2 = un2 + cb[1] * Bb[i].y;
        uo1[i] = s2 / (1.0f + expf(-s2));
    }
}

// ---------------------------------------------------------------------------

extern "C" void kernel_launch(void* const* d_in, const int* in_sizes, int n_in,
                              void* d_out, int out_size, void* d_ws, size_t ws_size,
                              hipStream_t stream) {
    const float* c    = (const float*)d_in[0];
    const float* bw0  = (const float*)d_in[1];
    const float* sw0  = (const float*)d_in[2];
    const float* bw1  = (const float*)d_in[3];
    const float* sw1  = (const float*)d_in[4];
    const float* bw2  = (const float*)d_in[5];
    const float* sw2  = (const float*)d_in[6];
    const float* sg   = (const float*)d_in[7];
    const float* dk   = (const float*)d_in[8];
    const float* pa   = (const float*)d_in[9];
    const float* pgam = (const float*)d_in[10];
    const float* ptau = (const float*)d_in[11];
    const float* pvel = (const float*)d_in[12];
    const float* gp   = (const float*)d_in[13];
    const float* chi  = (const float*)d_in[14];

    const int B = 4096, NIN = 512, W = 1024, NOUT = 1024;
    const int KE0 = 19 * NIN, KE1 = 19 * W;
    const size_t MN = (size_t)B * W;
    const size_t BE = (size_t)W * KE1 * 2;      // Bexp bytes (39.85 MB)
    dim3 blk(256);
    dim3 gblk(512);

    // ---- pick (CH, S): {4096,8} -> ring-2 kernel (2 blocks/CU) if ws fits;
    //      else S<=4 -> ring-4 kernel (verified best at current ws). ----
    struct Cand { int CH, S; };
    const Cand cands[] = {
        {4096, 8},
        {4096, 4}, {4096, 3}, {2048, 4}, {2048, 3}, {1024, 4},
        {512, 4}, {256, 4}
    };
    int CH = 0, S = 1;
    for (const auto& cd : cands) {
        size_t need = BE + (size_t)cd.CH * KE1 * 2 + (size_t)cd.S * MN * 4;
        if (need <= ws_size) { CH = cd.CH; S = cd.S; break; }
    }

    if (CH > 0) {
        f16* Bexp = (f16*)d_ws;
        float* P  = (float*)((char*)d_ws + BE);                // S planes of M x N fp32
        f16* Aexp = (f16*)((char*)d_ws + BE + (size_t)S * MN * 4);
        const bool deep = (S == 8);

        // ceil-split Kc (multiple of 32); kernel clamps last split
        const int Kc0 = ((KE0 / 32 + S - 1) / S) * 32;
        const int Kc1 = ((KE1 / 32 + S - 1) / S) * 32;

        // ---- layer 0: KIN=512 ----
        prep_b<<<(W * NIN) / 256, blk, 0, stream>>>(bw0, sw0, Bexp, NIN, 9);
        for (int r0 = 0; r0 < B; r0 += CH) {
            expand_sum_a<<<(CH * NIN) / 256, blk, 0, stream>>>(
                c + (size_t)r0 * NIN, 0, 1, Aexp, NIN, 9);
            if (deep)
                gemm_mfma2<<<dim3(W / 256, CH / 256, S), gblk, 0, stream>>>(
                    Aexp, Bexp, P + (size_t)r0 * W, KE0, Kc0, MN, W);
            else
                gemm_mfma<<<dim3(W / 256, CH / 256, S), gblk, 0, stream>>>(
                    Aexp, Bexp, P + (size_t)r0 * W, KE0, Kc0, MN, W);
        }
        // ---- layer 1: KIN=1024 ----
        prep_b<<<(W * W) / 256, blk, 0, stream>>>(bw1, sw1, Bexp, W, 10);
        for (int r0 = 0; r0 < B; r0 += CH) {
            expand_sum_a<<<(CH * W) / 256, blk, 0, stream>>>(
                P + (size_t)r0 * W, MN, S, Aexp, W, 10);
            if (deep)
                gemm_mfma2<<<dim3(W / 256, CH / 256, S), gblk, 0, stream>>>(
                    Aexp, Bexp, P + (size_t)r0 * W, KE1, Kc1, MN, W);
            else
                gemm_mfma<<<dim3(W / 256, CH / 256, S), gblk, 0, stream>>>(
                    Aexp, Bexp, P + (size_t)r0 * W, KE1, Kc1, MN, W);
        }
        // ---- layer 2 ----
        prep_b<<<(NOUT * W) / 256, blk, 0, stream>>>(bw2, sw2, Bexp, W, 10);
        for (int r0 = 0; r0 < B; r0 += CH) {
            expand_sum_a<<<(CH * W) / 256, blk, 0, stream>>>(
                P + (size_t)r0 * W, MN, S, Aexp, W, 10);
            if (deep)
                gemm_mfma2<<<dim3(NOUT / 256, CH / 256, S), gblk, 0, stream>>>(
                    Aexp, Bexp, P + (size_t)r0 * W, KE1, Kc1, MN, NOUT);
            else
                gemm_mfma<<<dim3(NOUT / 256, CH / 256, S), gblk, 0, stream>>>(
                    Aexp, Bexp, P + (size_t)r0 * W, KE1, Kc1, MN, NOUT);
        }
        huxley_kernel<<<B / 2, blk, 0, stream>>>(P, MN, S, (float*)d_out,
                                                 sg, dk, pa, pgam, ptau, pvel, gp, chi);
    } else {
        // fallback: round-1 fp32 path (needs only 33.6 MB ws)
        float* fx0 = (float*)d_ws;
        float* fx1 = fx0 + (size_t)B * W;
        dim3 g0(W / 64, B / 64);
        kan_gemm<<<g0, blk, 0, stream>>>(c,   bw0, sw0, fx0, NIN, W);
        kan_gemm<<<g0, blk, 0, stream>>>(fx0, bw1, sw1, fx1, W,   W);
        dim3 g2(NOUT / 64, B / 64);
        kan_gemm<<<g2, blk, 0, stream>>>(fx1, bw2, sw2, (float*)d_out, W, NOUT);
        huxley_kernel<<<B / 2, blk, 0, stream>>>((float*)d_out, 0, 1, (float*)d_out,
                                                 sg, dk, pa, pgam, ptau, pvel, gp, chi);
    }
}